// Round 16
// baseline (251.737 us; speedup 1.0000x reference)
//
#include <hip/hip_runtime.h>

#define HIDDEN_C 64
#define NCHUNK 256

typedef __attribute__((ext_vector_type(8))) short bf16x8;
typedef __attribute__((ext_vector_type(8))) unsigned short u16x8;
typedef __attribute__((ext_vector_type(4))) float f32x4;

__device__ __forceinline__ float4 f4zero() { return make_float4(0.f, 0.f, 0.f, 0.f); }

__device__ __forceinline__ unsigned short f2bf(float f) {
    unsigned u = __float_as_uint(f);
    u += 0x7FFF + ((u >> 16) & 1);          // round-to-nearest-even
    return (unsigned short)(u >> 16);
}
__device__ __forceinline__ float bf2f(unsigned short h) {
    return __uint_as_float(((unsigned)h) << 16);
}

// swizzled u16 index within a [rows][64 k] bf16 tile (128B rows, 16B-chunk XOR)
__device__ __forceinline__ int swz_idx(int row, int k) {
    return row * 64 + ((((k >> 3) ^ (row & 7)) << 3) | (k & 7));
}

// ---------------- generic exclusive scan ----------------
__global__ __launch_bounds__(256) void k_blocksum(const int* __restrict__ deg,
                                                  int* __restrict__ partial, int n) {
    int base = blockIdx.x * 1024 + threadIdx.x * 4;
    int s = 0;
#pragma unroll
    for (int k = 0; k < 4; ++k) {
        int i = base + k;
        if (i < n) s += deg[i];
    }
    __shared__ int red[256];
    red[threadIdx.x] = s;
    __syncthreads();
    for (int d = 128; d > 0; d >>= 1) {
        if (threadIdx.x < d) red[threadIdx.x] += red[threadIdx.x + d];
        __syncthreads();
    }
    if (threadIdx.x == 0) partial[blockIdx.x] = red[0];
}

__global__ __launch_bounds__(256) void k_scanpartial(int* __restrict__ partial,
                                                     int* __restrict__ last_slot,
                                                     int nBlocks, int nE) {
    __shared__ int buf[256];
    int tid = threadIdx.x;
    int v = (tid < nBlocks) ? partial[tid] : 0;
    buf[tid] = v;
    __syncthreads();
    for (int d = 1; d < 256; d <<= 1) {
        int t = (tid >= d) ? buf[tid - d] : 0;
        __syncthreads();
        buf[tid] += t;
        __syncthreads();
    }
    if (tid < nBlocks) partial[tid] = buf[tid] - v;
    if (tid == 0) last_slot[0] = nE;
}

__global__ __launch_bounds__(256) void k_writeptr(const int* __restrict__ deg,
                                                  const int* __restrict__ partial,
                                                  int* __restrict__ outp, int n) {
    int tid = threadIdx.x;
    int base = blockIdx.x * 1024 + tid * 4;
    int d[4];
    int s = 0;
#pragma unroll
    for (int k = 0; k < 4; ++k) {
        int i = base + k;
        d[k] = (i < n) ? deg[i] : 0;
        s += d[k];
    }
    __shared__ int buf[256];
    buf[tid] = s;
    __syncthreads();
    for (int dd = 1; dd < 256; dd <<= 1) {
        int t = (tid >= dd) ? buf[tid - dd] : 0;
        __syncthreads();
        buf[tid] += t;
        __syncthreads();
    }
    int off = partial[blockIdx.x] + buf[tid] - s;
#pragma unroll
    for (int k = 0; k < 4; ++k) {
        int i = base + k;
        if (i < n) {
            outp[i] = off;
            off += d[k];
        }
    }
}

// ---------------- bucket partition (bucket = dst>>6) ----------------
__global__ __launch_bounds__(256) void k_bcount(const int* __restrict__ dst,
                                                int* __restrict__ cnt,
                                                int nE, int chunkSz, int nBuckets) {
    __shared__ int h[1024];
    int c = blockIdx.x, tid = threadIdx.x;
    for (int i = tid; i < nBuckets; i += 256) h[i] = 0;
    __syncthreads();
    int beg = c * chunkSz;
    int end = beg + chunkSz; if (end > nE) end = nE;
    int e = beg + tid;
    for (; e + 256 < end; e += 512) {
        int d0 = dst[e];
        int d1 = dst[e + 256];
        atomicAdd(&h[d0 >> 6], 1);
        atomicAdd(&h[d1 >> 6], 1);
    }
    if (e < end) atomicAdd(&h[dst[e] >> 6], 1);
    __syncthreads();
    for (int i = tid; i < nBuckets; i += 256) cnt[i * NCHUNK + c] = h[i];
}

__global__ __launch_bounds__(256) void k_bscatter(const int* __restrict__ src,
                                                  const int* __restrict__ dst,
                                                  const int* __restrict__ eoff,
                                                  unsigned* __restrict__ ebuf,
                                                  int nE, int chunkSz, int nBuckets) {
    __shared__ int cur[1024];
    int c = blockIdx.x, tid = threadIdx.x;
    for (int i = tid; i < nBuckets; i += 256) cur[i] = eoff[i * NCHUNK + c];
    __syncthreads();
    int beg = c * chunkSz;
    int end = beg + chunkSz; if (end > nE) end = nE;
    int e = beg + tid;
    for (; e + 256 < end; e += 512) {
        int d0 = dst[e];
        int d1 = dst[e + 256];
        int s0 = src[e];
        int s1 = src[e + 256];
        int p0 = atomicAdd(&cur[d0 >> 6], 1);
        int p1 = atomicAdd(&cur[d1 >> 6], 1);
        ebuf[p0] = ((unsigned)(d0 & 63) << 16) | (unsigned)s0;  // nNodes<=65536
        ebuf[p1] = ((unsigned)(d1 & 63) << 16) | (unsigned)s1;
    }
    if (e < end) {
        int d = dst[e];
        int pos = atomicAdd(&cur[d >> 6], 1);
        ebuf[pos] = ((unsigned)(d & 63) << 16) | (unsigned)src[e];
    }
}

__global__ __launch_bounds__(256) void k_bfill(const unsigned* __restrict__ ebuf,
                                               const int* __restrict__ eoff,
                                               int* __restrict__ rowptr,
                                               int* __restrict__ col,
                                               int nNodes, int nE, int nBuckets) {
    __shared__ int deg[64], cur[64];
    int b = blockIdx.x, tid = threadIdx.x;
    int lo = eoff[b * NCHUNK];
    int hi = (b + 1 < nBuckets) ? eoff[(b + 1) * NCHUNK] : nE;
    if (tid < 64) deg[tid] = 0;
    __syncthreads();
    for (int e = lo + tid; e < hi; e += 256) atomicAdd(&deg[ebuf[e] >> 16], 1);
    __syncthreads();
    if (tid < 64) {
        int d = deg[tid];
        int s = d;
        for (int o = 1; o < 64; o <<= 1) {
            int t = __shfl_up(s, o, 64);
            if (tid >= o) s += t;
        }
        int st = s - d;
        cur[tid] = lo + st;
        int node = b * 64 + tid;
        if (node < nNodes) rowptr[node] = lo + st;
    }
    __syncthreads();
    for (int e = lo + tid; e < hi; e += 256) {
        unsigned pk = ebuf[e];
        int pos = atomicAdd(&cur[pk >> 16], 1);
        col[pos] = (int)(pk & 0xFFFFu);
    }
}

// ---------------- weight prep: W[k][f] fp32 -> W^T hi/lo bf16 swizzled tiles ----------------
__global__ __launch_bounds__(256) void k_wprep(const float* __restrict__ W1,
                                               const float* __restrict__ W2,
                                               unsigned short* __restrict__ wt) {
    __shared__ unsigned short s[8192];
    int b = blockIdx.x;
    int layer = b >> 1;
    const float* src = ((b & 1) ? W2 : W1) + (size_t)layer * 4096;
    int tid = threadIdx.x;
    int k = tid >> 2;
    int f0 = (tid & 3) * 16;
    const float* srcp = src + k * 64 + f0;
#pragma unroll
    for (int j4 = 0; j4 < 4; ++j4) {
        float4 wv = *(const float4*)(srcp + j4 * 4);
        float c[4] = {wv.x, wv.y, wv.z, wv.w};
        int f = f0 + j4 * 4;
#pragma unroll
        for (int j = 0; j < 4; ++j) {
            unsigned short h = f2bf(c[j]);
            int ix = swz_idx(f + j, k);
            s[ix] = h;
            s[4096 + ix] = f2bf(c[j] - bf2f(h));
        }
    }
    __syncthreads();
    uint4* dst = (uint4*)(wt + (size_t)b * 8192);
    const uint4* sp = (const uint4*)s;
#pragma unroll
    for (int it = 0; it < 4; ++it) dst[it * 256 + tid] = sp[it * 256 + tid];
}

// ---------------- per-stat reduction of block partials (atomic-free BN stats) ----------------
__global__ __launch_bounds__(256) void k_statred(const float* __restrict__ pstat,
                                                 float* __restrict__ stats, int nb) {
    int j = blockIdx.x;          // stat index 0..127
    int tid = threadIdx.x;
    float s = 0.f;
    for (int b = tid; b < nb; b += 256) s += pstat[(size_t)b * 128 + j];
    __shared__ float red[256];
    red[tid] = s;
    __syncthreads();
    for (int d = 128; d > 0; d >>= 1) {
        if (tid < d) red[tid] += red[tid + d];
        __syncthreads();
    }
    if (tid == 0) stats[j] = red[0];
}

// ---------------- FUSED layer: BN(prev)+gather -> MFMA 2-layer MLP -> stats ----------------
// gather: wave = 16 nodes serially; 4 lane-groups x 16 lanes (float4) = 4 rows/load-instr,
// shfl-xor reduce, result written directly into the swizzled hi/lo LDS A-tile.
// GEMM: 16x16x32 bf16 MFMA, split hi/lo (bit-identical to round-15 k_mlp).
template <bool DOBN>
__global__ __launch_bounds__(256, 5) void k_layer(const float4* __restrict__ x4,
                                                  const int* __restrict__ rowptr,
                                                  const int* __restrict__ col,
                                                  const float* __restrict__ stats,
                                                  const float* __restrict__ gamma,
                                                  const float* __restrict__ beta,
                                                  const unsigned short* __restrict__ wt1,
                                                  const float* __restrict__ b1,
                                                  const unsigned short* __restrict__ wt2,
                                                  const float* __restrict__ b2,
                                                  float* __restrict__ pstat,
                                                  float* __restrict__ h_out,
                                                  int nNodes, float invN) {
    __shared__ __align__(16) unsigned short smem16[16384];   // 32KB
    unsigned short* sA_hi = smem16;            // [64][64] bf16 swz (A, then h1)
    unsigned short* sA_lo = smem16 + 4096;
    unsigned short* sW_hi = smem16 + 8192;     // W^T tile hi (W1, then W2)
    unsigned short* sW_lo = smem16 + 12288;    // W^T tile lo

    int tid = threadIdx.x;
    int n0 = blockIdx.x * 64;
    int lane = tid & 63;
    int w = tid >> 6;
    int lr = lane & 15;
    int q = lane >> 4;
    int r0 = w * 16;
    int grp = lane >> 4;       // 0..3 (edge group)
    int l16 = lane & 15;       // float4 slot

    // --- prefetch FULL W2^T (hi+lo = 1024 uint4) into registers ---
    uint4 w2r[4];
#pragma unroll
    for (int it = 0; it < 4; ++it) w2r[it] = ((const uint4*)wt2)[it * 256 + tid];

    // --- copy FULL W1^T hi/lo (1024 uint4) ---
    {
        uint4* d = (uint4*)sW_hi;
        const uint4* s = (const uint4*)wt1;
#pragma unroll
        for (int it = 0; it < 4; ++it) d[it * 256 + tid] = s[it * 256 + tid];
    }

    // --- BN(prev) coefficients for this lane's 4 features ---
    float4 sc = make_float4(1.f, 1.f, 1.f, 1.f);
    float4 sh = f4zero();
    if (DOBN) {
        float4 s  = ((const float4*)stats)[l16];
        float4 qv = ((const float4*)stats)[16 + l16];
        float4 ga = ((const float4*)gamma)[l16];
        float4 be = ((const float4*)beta)[l16];
        float m;
        m = s.x * invN; sc.x = ga.x * rsqrtf(qv.x * invN - m * m + 1e-5f); sh.x = be.x - m * sc.x;
        m = s.y * invN; sc.y = ga.y * rsqrtf(qv.y * invN - m * m + 1e-5f); sh.y = be.y - m * sc.y;
        m = s.z * invN; sc.z = ga.z * rsqrtf(qv.z * invN - m * m + 1e-5f); sh.z = be.z - m * sc.z;
        m = s.w * invN; sc.w = ga.w * rsqrtf(qv.w * invN - m * m + 1e-5f); sh.w = be.w - m * sc.w;
    }

#define APPLYBN(V)                                          \
    if (DOBN) {                                             \
        V.x = fmaxf(fmaf(V.x, sc.x, sh.x), 0.f);            \
        V.y = fmaxf(fmaf(V.y, sc.y, sh.y), 0.f);            \
        V.z = fmaxf(fmaf(V.z, sc.z, sh.z), 0.f);            \
        V.w = fmaxf(fmaf(V.w, sc.w, sh.w), 0.f);            \
    }

    // --- gather: this wave's 16 rows -> swizzled hi/lo A-tile ---
    for (int i = 0; i < 16; ++i) {
        int rloc = r0 + i;
        int n = n0 + rloc;
        float4 acc = f4zero();
        if (n < nNodes) {
            if (grp == 0) {
                float4 v = x4[(size_t)n * 16 + l16];
                APPLYBN(v)
                acc = v;
            }
            int lo = rowptr[n], hi = rowptr[n + 1];
            int e = lo;
            for (; e + 8 <= hi; e += 8) {
                int i0 = col[e + grp];
                int i1 = col[e + 4 + grp];
                float4 v0 = x4[(size_t)i0 * 16 + l16];
                float4 v1 = x4[(size_t)i1 * 16 + l16];
                APPLYBN(v0)
                APPLYBN(v1)
                acc.x += v0.x + v1.x; acc.y += v0.y + v1.y;
                acc.z += v0.z + v1.z; acc.w += v0.w + v1.w;
            }
            for (; e < hi; e += 4) {
                int ee = e + grp;
                bool ok = ee < hi;
                int idx = col[ok ? ee : (hi - 1)];
                float4 v = x4[(size_t)idx * 16 + l16];
                APPLYBN(v)
                if (ok) {
                    acc.x += v.x; acc.y += v.y; acc.z += v.z; acc.w += v.w;
                }
            }
        }
        acc.x += __shfl_xor(acc.x, 16, 64); acc.y += __shfl_xor(acc.y, 16, 64);
        acc.z += __shfl_xor(acc.z, 16, 64); acc.w += __shfl_xor(acc.w, 16, 64);
        acc.x += __shfl_xor(acc.x, 32, 64); acc.y += __shfl_xor(acc.y, 32, 64);
        acc.z += __shfl_xor(acc.z, 32, 64); acc.w += __shfl_xor(acc.w, 32, 64);

        if (lane < 16) {
            // features k = l16*4 .. +3 ; write 4 u16 hi + 4 u16 lo at swizzled pos
            ushort4 hv, lv;
            hv.x = f2bf(acc.x); lv.x = f2bf(acc.x - bf2f(hv.x));
            hv.y = f2bf(acc.y); lv.y = f2bf(acc.y - bf2f(hv.y));
            hv.z = f2bf(acc.z); lv.z = f2bf(acc.z - bf2f(hv.z));
            hv.w = f2bf(acc.w); lv.w = f2bf(acc.w - bf2f(hv.w));
            int ix = rloc * 64 + ((((l16 >> 1) ^ (rloc & 7)) << 3) | ((l16 & 1) << 2));
            *(ushort4*)(sA_hi + ix) = hv;
            *(ushort4*)(sA_lo + ix) = lv;
        }
    }
#undef APPLYBN
    __syncthreads();

    f32x4 acc[4];

#define GEMM_SPLIT(BIAS)                                                         \
    {                                                                            \
        int rowA = r0 + lr;                                                      \
        const unsigned short* pah = sA_hi + rowA * 64;                           \
        const unsigned short* pal = sA_lo + rowA * 64;                           \
        int sr = rowA & 7;                                                       \
        bf16x8 ah0 = *(const bf16x8*)(pah + ((q ^ sr) << 3));                    \
        bf16x8 ah1 = *(const bf16x8*)(pah + (((4 + q) ^ sr) << 3));              \
        bf16x8 al0 = *(const bf16x8*)(pal + ((q ^ sr) << 3));                    \
        bf16x8 al1 = *(const bf16x8*)(pal + (((4 + q) ^ sr) << 3));              \
        _Pragma("unroll")                                                        \
        for (int ct = 0; ct < 4; ++ct) {                                         \
            int f = ct * 16 + lr;                                                \
            const unsigned short* pbh = sW_hi + f * 64;                          \
            const unsigned short* pbl = sW_lo + f * 64;                          \
            int sf = f & 7;                                                      \
            bf16x8 bh0 = *(const bf16x8*)(pbh + ((q ^ sf) << 3));                \
            bf16x8 bh1 = *(const bf16x8*)(pbh + (((4 + q) ^ sf) << 3));          \
            bf16x8 bl0 = *(const bf16x8*)(pbl + ((q ^ sf) << 3));                \
            bf16x8 bl1 = *(const bf16x8*)(pbl + (((4 + q) ^ sf) << 3));          \
            float bias = BIAS[f];                                                \
            f32x4 c = {bias, bias, bias, bias};                                  \
            c = __builtin_amdgcn_mfma_f32_16x16x32_bf16(al0, bh0, c, 0, 0, 0);   \
            c = __builtin_amdgcn_mfma_f32_16x16x32_bf16(al1, bh1, c, 0, 0, 0);   \
            c = __builtin_amdgcn_mfma_f32_16x16x32_bf16(ah0, bl0, c, 0, 0, 0);   \
            c = __builtin_amdgcn_mfma_f32_16x16x32_bf16(ah1, bl1, c, 0, 0, 0);   \
            c = __builtin_amdgcn_mfma_f32_16x16x32_bf16(ah0, bh0, c, 0, 0, 0);   \
            c = __builtin_amdgcn_mfma_f32_16x16x32_bf16(ah1, bh1, c, 0, 0, 0);   \
            acc[ct] = c;                                                         \
        }                                                                        \
    }

    // ---- GEMM1: h1 = relu(h @ W1 + b1) ----
    GEMM_SPLIT(b1)

    __syncthreads();   // all GEMM1 LDS reads done; sA & sW reusable

    // h1 -> sA region hi/lo; W2 regs (full hi+lo) -> sW
#pragma unroll
    for (int ct = 0; ct < 4; ++ct) {
        int f = ct * 16 + lr;
#pragma unroll
        for (int rg = 0; rg < 4; ++rg) {
            int row = r0 + q * 4 + rg;
            float v = fmaxf(acc[ct][rg], 0.f);
            unsigned short h = f2bf(v);
            int ix = swz_idx(row, f);
            sA_hi[ix] = h;
            sA_lo[ix] = f2bf(v - bf2f(h));
        }
    }
    {
        uint4* d = (uint4*)sW_hi;
#pragma unroll
        for (int it = 0; it < 4; ++it) d[it * 256 + tid] = w2r[it];
    }
    __syncthreads();

    // ---- GEMM2: out = relu(h1 @ W2 + b2) ----
    GEMM_SPLIT(b2)

    __syncthreads();   // all GEMM2 LDS reads done; sW reusable as stats scratch
#undef GEMM_SPLIT

    float* sS = (float*)sW_hi;     // [4][64] sums
    float* sQ = sS + 256;          // [4][64] sumsq

    // epilogue: relu -> global store + register stats
#pragma unroll
    for (int ct = 0; ct < 4; ++ct) {
        int f = ct * 16 + lr;
        float sp = 0.f, qp = 0.f;
#pragma unroll
        for (int rg = 0; rg < 4; ++rg) {
            int row = r0 + q * 4 + rg;
            float v = fmaxf(acc[ct][rg], 0.f);
            if (n0 + row < nNodes) {
                h_out[(size_t)(n0 + row) * 64 + f] = v;
                sp += v;
                qp += v * v;
            }
        }
        sp += __shfl_xor(sp, 16, 64); qp += __shfl_xor(qp, 16, 64);
        sp += __shfl_xor(sp, 32, 64); qp += __shfl_xor(qp, 32, 64);
        if (q == 0) {
            sS[w * 64 + f] = sp;
            sQ[w * 64 + f] = qp;
        }
    }
    __syncthreads();
    // atomic-free: one contiguous 512B partial record per block
    if (tid < 128) {
        float v;
        if (tid < 64)
            v = sS[tid] + sS[64 + tid] + sS[128 + tid] + sS[192 + tid];
        else {
            int f = tid - 64;
            v = sQ[f] + sQ[64 + f] + sQ[128 + f] + sQ[192 + f];
        }
        pstat[(size_t)blockIdx.x * 128 + tid] = v;
    }
}

// ---------------- pooling (BN3 fused) + final GEMV ----------------
__device__ __forceinline__ int lower_bound_dev(const int* a, int n, int key) {
    int lo = 0, hi = n;
    while (lo < hi) {
        int mid = (lo + hi) >> 1;
        if (a[mid] < key) lo = mid + 1; else hi = mid;
    }
    return lo;
}

__global__ __launch_bounds__(256) void k_pool(const float4* __restrict__ x4,
                                              const int* __restrict__ batch,
                                              const float* __restrict__ stats,
                                              const float* __restrict__ gamma,
                                              const float* __restrict__ beta,
                                              const float* __restrict__ Wf,
                                              const float* __restrict__ bf,
                                              float* __restrict__ out,
                                              int nNodes, float invN) {
    int wid = threadIdx.x >> 6;
    int lane = threadIdx.x & 63;
    int grp = lane >> 4;
    int l16 = lane & 15;
    int g = blockIdx.x * 4 + wid;

    float4 sc, sh;
    {
        float4 s  = ((const float4*)stats)[l16];
        float4 q  = ((const float4*)stats)[16 + l16];
        float4 ga = ((const float4*)gamma)[l16];
        float4 be = ((const float4*)beta)[l16];
        float m;
        m = s.x * invN; sc.x = ga.x * rsqrtf(q.x * invN - m * m + 1e-5f); sh.x = be.x - m * sc.x;
        m = s.y * invN; sc.y = ga.y * rsqrtf(q.y * invN - m * m + 1e-5f); sh.y = be.y - m * sc.y;
        m = s.z * invN; sc.z = ga.z * rsqrtf(q.z * invN - m * m + 1e-5f); sh.z = be.z - m * sc.z;
        m = s.w * invN; sc.w = ga.w * rsqrtf(q.w * invN - m * m + 1e-5f); sh.w = be.w - m * sc.w;
    }

    int lo = lower_bound_dev(batch, nNodes, g);
    int hi = lower_bound_dev(batch, nNodes, g + 1);

    float4 acc = f4zero();
    for (int r = lo + grp; r < hi; r += 4) {
        float4 v = x4[(size_t)r * 16 + l16];
        acc.x += fmaxf(fmaf(v.x, sc.x, sh.x), 0.f);
        acc.y += fmaxf(fmaf(v.y, sc.y, sh.y), 0.f);
        acc.z += fmaxf(fmaf(v.z, sc.z, sh.z), 0.f);
        acc.w += fmaxf(fmaf(v.w, sc.w, sh.w), 0.f);
    }
    acc.x += __shfl_xor(acc.x, 16, 64); acc.y += __shfl_xor(acc.y, 16, 64);
    acc.z += __shfl_xor(acc.z, 16, 64); acc.w += __shfl_xor(acc.w, 16, 64);
    acc.x += __shfl_xor(acc.x, 32, 64); acc.y += __shfl_xor(acc.y, 32, 64);
    acc.z += __shfl_xor(acc.z, 32, 64); acc.w += __shfl_xor(acc.w, 32, 64);

    float4 wf = ((const float4*)Wf)[l16];
    float p = acc.x * wf.x + acc.y * wf.y + acc.z * wf.z + acc.w * wf.w;
    p += __shfl_xor(p, 1, 64);
    p += __shfl_xor(p, 2, 64);
    p += __shfl_xor(p, 4, 64);
    p += __shfl_xor(p, 8, 64);
    if (lane == 0) out[g] = p + bf[0];
}

extern "C" void kernel_launch(void* const* d_in, const int* in_sizes, int n_in,
                              void* d_out, int out_size, void* d_ws, size_t ws_size,
                              hipStream_t stream) {
    const float* x_in  = (const float*)d_in[0];
    const int*   ei    = (const int*)d_in[1];
    const int*   batch = (const int*)d_in[2];
    const float* W1    = (const float*)d_in[3];
    const float* b1    = (const float*)d_in[4];
    const float* W2    = (const float*)d_in[5];
    const float* b2    = (const float*)d_in[6];
    const float* gamma = (const float*)d_in[7];
    const float* beta  = (const float*)d_in[8];
    const float* Wf    = (const float*)d_in[9];
    const float* bf    = (const float*)d_in[10];

    const int nNodes = in_sizes[0] / HIDDEN_C;   // 50000 (pack assumes <= 65536)
    const int nE = in_sizes[1] / 2;              // 800000
    const int* src = ei;
    const int* dst = ei + nE;

    const int nBuckets = (nNodes + 63) / 64;         // 782
    const int nTot = nBuckets * NCHUNK;              // 200192
    const int chunkSz = (nE + NCHUNK - 1) / NCHUNK;  // 3125
    const int scanBlocks = (nTot + 1023) / 1024;     // 196 (<=256)
    const float invN = 1.f / (float)nNodes;

    const size_t NB = (size_t)nNodes * HIDDEN_C * sizeof(float);  // 12.8 MB
    char* ws = (char*)d_ws;
    float*    bufA    = (float*)ws;
    float*    bufB    = (float*)(ws + NB);
    float*    stats   = (float*)(ws + 2 * NB);              // 3 x 128 floats
    unsigned short* wtbuf = (unsigned short*)(ws + 2 * NB + 4096);   // 6 x 8192 u16 = 96KB
    float*    pstat   = (float*)(ws + 2 * NB + 4096 + 98304);        // 800 x 128 floats = 400KB
    int*      rowptr  = (int*)((char*)pstat + 409600);      // nNodes+1
    int*      partial = rowptr + nNodes + 64;               // 256
    int*      col     = partial + 256;                      // nE
    // transient CSR-build scratch aliased into bufB (bufB first written at layer-1 output)
    unsigned* ebuf    = (unsigned*)bufB;                    // nE (3.2MB)
    int*      cnt     = (int*)((char*)bufB + (size_t)nE * 4);  // nTot (0.8MB)
    int*      eoff    = cnt + nTot + 64;                    // nTot (0.8MB)

    const int layerGrid = nBuckets;                         // 782 (64-row tiles)

    // ---- weight prep (once) + CSR build via 64-node buckets ----
    k_wprep<<<6, 256, 0, stream>>>(W1, W2, wtbuf);
    k_bcount<<<NCHUNK, 256, 0, stream>>>(dst, cnt, nE, chunkSz, nBuckets);
    k_blocksum<<<scanBlocks, 256, 0, stream>>>(cnt, partial, nTot);
    k_scanpartial<<<1, 256, 0, stream>>>(partial, rowptr + nNodes, scanBlocks, nE);
    k_writeptr<<<scanBlocks, 256, 0, stream>>>(cnt, partial, eoff, nTot);
    k_bscatter<<<NCHUNK, 256, 0, stream>>>(src, dst, eoff, ebuf, nE, chunkSz, nBuckets);
    k_bfill<<<nBuckets, 256, 0, stream>>>(ebuf, eoff, rowptr, col, nNodes, nE, nBuckets);

    // ---- 3 fused layers: gather+BN(prev) -> split-MFMA MLP -> partial stats ----
    const float* prev_h = x_in;
    float* cur = bufA;
    for (int i = 0; i < 3; ++i) {
        if (i == 0) {
            k_layer<false><<<layerGrid, 256, 0, stream>>>((const float4*)prev_h, rowptr, col,
                nullptr, nullptr, nullptr,
                wtbuf, b1, wtbuf + 8192, b2,
                pstat, cur, nNodes, invN);
        } else {
            k_layer<true><<<layerGrid, 256, 0, stream>>>((const float4*)prev_h, rowptr, col,
                stats + (size_t)(i - 1) * 128, gamma + (size_t)(i - 1) * 64, beta + (size_t)(i - 1) * 64,
                wtbuf + (size_t)(2 * i) * 8192, b1 + (size_t)i * 64,
                wtbuf + (size_t)(2 * i + 1) * 8192, b2 + (size_t)i * 64,
                pstat, cur, nNodes, invN);
        }
        k_statred<<<128, 256, 0, stream>>>(pstat, stats + (size_t)i * 128, nBuckets);
        prev_h = cur;
        cur = (cur == bufA) ? bufB : bufA;
    }

    k_pool<<<64, 256, 0, stream>>>((const float4*)prev_h, batch,
                                   stats + 256, gamma + 128, beta + 128,
                                   Wf, bf, (float*)d_out, nNodes, invN);
}

// Round 17
// 201.938 us; speedup vs baseline: 1.2466x; 1.2466x over previous
//
#include <hip/hip_runtime.h>

#define HIDDEN_C 64
#define NCHUNK 256

typedef __attribute__((ext_vector_type(8))) short bf16x8;
typedef __attribute__((ext_vector_type(8))) unsigned short u16x8;
typedef __attribute__((ext_vector_type(4))) float f32x4;

__device__ __forceinline__ float4 f4zero() { return make_float4(0.f, 0.f, 0.f, 0.f); }

__device__ __forceinline__ unsigned short f2bf(float f) {
    unsigned u = __float_as_uint(f);
    u += 0x7FFF + ((u >> 16) & 1);          // round-to-nearest-even
    return (unsigned short)(u >> 16);
}
__device__ __forceinline__ float bf2f(unsigned short h) {
    return __uint_as_float(((unsigned)h) << 16);
}
__device__ __forceinline__ unsigned short f2h(float f) {
    _Float16 h = (_Float16)f;
    unsigned short u;
    __builtin_memcpy(&u, &h, 2);
    return u;
}
__device__ __forceinline__ float h2f(unsigned short u) {
    _Float16 h;
    __builtin_memcpy(&h, &u, 2);
    return (float)h;
}

// swizzled u16 index within a [rows][64 k] bf16 tile (128B rows, 16B-chunk XOR)
__device__ __forceinline__ int swz_idx(int row, int k) {
    return row * 64 + ((((k >> 3) ^ (row & 7)) << 3) | (k & 7));
}

// ---------------- fp32 -> fp16 input conversion (once) ----------------
__global__ __launch_bounds__(256) void k_xcvt(const float4* __restrict__ in,
                                              ushort4* __restrict__ out, int n4) {
    int i = blockIdx.x * 256 + threadIdx.x;
    if (i < n4) {
        float4 v = in[i];
        ushort4 o;
        o.x = f2h(v.x); o.y = f2h(v.y); o.z = f2h(v.z); o.w = f2h(v.w);
        out[i] = o;
    }
}

// ---------------- generic exclusive scan ----------------
__global__ __launch_bounds__(256) void k_blocksum(const int* __restrict__ deg,
                                                  int* __restrict__ partial, int n) {
    int base = blockIdx.x * 1024 + threadIdx.x * 4;
    int s = 0;
#pragma unroll
    for (int k = 0; k < 4; ++k) {
        int i = base + k;
        if (i < n) s += deg[i];
    }
    __shared__ int red[256];
    red[threadIdx.x] = s;
    __syncthreads();
    for (int d = 128; d > 0; d >>= 1) {
        if (threadIdx.x < d) red[threadIdx.x] += red[threadIdx.x + d];
        __syncthreads();
    }
    if (threadIdx.x == 0) partial[blockIdx.x] = red[0];
}

__global__ __launch_bounds__(256) void k_scanpartial(int* __restrict__ partial,
                                                     int* __restrict__ last_slot,
                                                     int nBlocks, int nE) {
    __shared__ int buf[256];
    int tid = threadIdx.x;
    int v = (tid < nBlocks) ? partial[tid] : 0;
    buf[tid] = v;
    __syncthreads();
    for (int d = 1; d < 256; d <<= 1) {
        int t = (tid >= d) ? buf[tid - d] : 0;
        __syncthreads();
        buf[tid] += t;
        __syncthreads();
    }
    if (tid < nBlocks) partial[tid] = buf[tid] - v;
    if (tid == 0) last_slot[0] = nE;
}

__global__ __launch_bounds__(256) void k_writeptr(const int* __restrict__ deg,
                                                  const int* __restrict__ partial,
                                                  int* __restrict__ outp, int n) {
    int tid = threadIdx.x;
    int base = blockIdx.x * 1024 + tid * 4;
    int d[4];
    int s = 0;
#pragma unroll
    for (int k = 0; k < 4; ++k) {
        int i = base + k;
        d[k] = (i < n) ? deg[i] : 0;
        s += d[k];
    }
    __shared__ int buf[256];
    buf[tid] = s;
    __syncthreads();
    for (int dd = 1; dd < 256; dd <<= 1) {
        int t = (tid >= dd) ? buf[tid - dd] : 0;
        __syncthreads();
        buf[tid] += t;
        __syncthreads();
    }
    int off = partial[blockIdx.x] + buf[tid] - s;
#pragma unroll
    for (int k = 0; k < 4; ++k) {
        int i = base + k;
        if (i < n) {
            outp[i] = off;
            off += d[k];
        }
    }
}

// ---------------- bucket partition (bucket = dst>>6) ----------------
__global__ __launch_bounds__(256) void k_bcount(const int* __restrict__ dst,
                                                int* __restrict__ cnt,
                                                int nE, int chunkSz, int nBuckets) {
    __shared__ int h[1024];
    int c = blockIdx.x, tid = threadIdx.x;
    for (int i = tid; i < nBuckets; i += 256) h[i] = 0;
    __syncthreads();
    int beg = c * chunkSz;
    int end = beg + chunkSz; if (end > nE) end = nE;
    int e = beg + tid;
    for (; e + 256 < end; e += 512) {
        int d0 = dst[e];
        int d1 = dst[e + 256];
        atomicAdd(&h[d0 >> 6], 1);
        atomicAdd(&h[d1 >> 6], 1);
    }
    if (e < end) atomicAdd(&h[dst[e] >> 6], 1);
    __syncthreads();
    for (int i = tid; i < nBuckets; i += 256) cnt[i * NCHUNK + c] = h[i];
}

__global__ __launch_bounds__(256) void k_bscatter(const int* __restrict__ src,
                                                  const int* __restrict__ dst,
                                                  const int* __restrict__ eoff,
                                                  unsigned* __restrict__ ebuf,
                                                  int nE, int chunkSz, int nBuckets) {
    __shared__ int cur[1024];
    int c = blockIdx.x, tid = threadIdx.x;
    for (int i = tid; i < nBuckets; i += 256) cur[i] = eoff[i * NCHUNK + c];
    __syncthreads();
    int beg = c * chunkSz;
    int end = beg + chunkSz; if (end > nE) end = nE;
    int e = beg + tid;
    for (; e + 256 < end; e += 512) {
        int d0 = dst[e];
        int d1 = dst[e + 256];
        int s0 = src[e];
        int s1 = src[e + 256];
        int p0 = atomicAdd(&cur[d0 >> 6], 1);
        int p1 = atomicAdd(&cur[d1 >> 6], 1);
        ebuf[p0] = ((unsigned)(d0 & 63) << 16) | (unsigned)s0;  // nNodes<=65536
        ebuf[p1] = ((unsigned)(d1 & 63) << 16) | (unsigned)s1;
    }
    if (e < end) {
        int d = dst[e];
        int pos = atomicAdd(&cur[d >> 6], 1);
        ebuf[pos] = ((unsigned)(d & 63) << 16) | (unsigned)src[e];
    }
}

__global__ __launch_bounds__(256) void k_bfill(const unsigned* __restrict__ ebuf,
                                               const int* __restrict__ eoff,
                                               int* __restrict__ rowptr,
                                               int* __restrict__ col,
                                               int nNodes, int nE, int nBuckets) {
    __shared__ int deg[64], cur[64];
    int b = blockIdx.x, tid = threadIdx.x;
    int lo = eoff[b * NCHUNK];
    int hi = (b + 1 < nBuckets) ? eoff[(b + 1) * NCHUNK] : nE;
    if (tid < 64) deg[tid] = 0;
    __syncthreads();
    for (int e = lo + tid; e < hi; e += 256) atomicAdd(&deg[ebuf[e] >> 16], 1);
    __syncthreads();
    if (tid < 64) {
        int d = deg[tid];
        int s = d;
        for (int o = 1; o < 64; o <<= 1) {
            int t = __shfl_up(s, o, 64);
            if (tid >= o) s += t;
        }
        int st = s - d;
        cur[tid] = lo + st;
        int node = b * 64 + tid;
        if (node < nNodes) rowptr[node] = lo + st;
    }
    __syncthreads();
    for (int e = lo + tid; e < hi; e += 256) {
        unsigned pk = ebuf[e];
        int pos = atomicAdd(&cur[pk >> 16], 1);
        col[pos] = (int)(pk & 0xFFFFu);
    }
}

// ---------------- weight prep: W[k][f] fp32 -> W^T hi/lo bf16 swizzled tiles ----------------
__global__ __launch_bounds__(256) void k_wprep(const float* __restrict__ W1,
                                               const float* __restrict__ W2,
                                               unsigned short* __restrict__ wt) {
    __shared__ unsigned short s[8192];
    int b = blockIdx.x;
    int layer = b >> 1;
    const float* src = ((b & 1) ? W2 : W1) + (size_t)layer * 4096;
    int tid = threadIdx.x;
    int k = tid >> 2;
    int f0 = (tid & 3) * 16;
    const float* srcp = src + k * 64 + f0;
#pragma unroll
    for (int j4 = 0; j4 < 4; ++j4) {
        float4 wv = *(const float4*)(srcp + j4 * 4);
        float c[4] = {wv.x, wv.y, wv.z, wv.w};
        int f = f0 + j4 * 4;
#pragma unroll
        for (int j = 0; j < 4; ++j) {
            unsigned short h = f2bf(c[j]);
            int ix = swz_idx(f + j, k);
            s[ix] = h;
            s[4096 + ix] = f2bf(c[j] - bf2f(h));
        }
    }
    __syncthreads();
    uint4* dst = (uint4*)(wt + (size_t)b * 8192);
    const uint4* sp = (const uint4*)s;
#pragma unroll
    for (int it = 0; it < 4; ++it) dst[it * 256 + tid] = sp[it * 256 + tid];
}

// ---------------- per-stat reduction of block partials (atomic-free BN stats) ----------------
__global__ __launch_bounds__(256) void k_statred(const float* __restrict__ pstat,
                                                 float* __restrict__ stats, int nb) {
    int j = blockIdx.x;          // stat index 0..127
    int tid = threadIdx.x;
    float s = 0.f;
    for (int b = tid; b < nb; b += 256) s += pstat[(size_t)b * 128 + j];
    __shared__ float red[256];
    red[tid] = s;
    __syncthreads();
    for (int d = 128; d > 0; d >>= 1) {
        if (tid < d) red[tid] += red[tid + d];
        __syncthreads();
    }
    if (tid == 0) stats[j] = red[0];
}

// ---------------- fused BN(prev layer) + gather aggregation (fp16 storage, fp32 math) ----------------
template <bool DOBN>
__global__ __launch_bounds__(256) void k_aggbn(const unsigned short* __restrict__ x16,
                                               const int* __restrict__ rowptr,
                                               const int* __restrict__ col,
                                               const float* __restrict__ stats,
                                               const float* __restrict__ gamma,
                                               const float* __restrict__ beta,
                                               unsigned short* __restrict__ hout,
                                               int nNodes, float invN) {
    int wid = threadIdx.x >> 6;
    int lane = threadIdx.x & 63;
    int grp = lane >> 4;
    int l16 = lane & 15;
    int n = blockIdx.x * 4 + wid;
    if (n >= nNodes) return;

    float4 sc = make_float4(1.f, 1.f, 1.f, 1.f);
    float4 sh = f4zero();
    if (DOBN) {
        float4 s  = ((const float4*)stats)[l16];
        float4 q  = ((const float4*)stats)[16 + l16];
        float4 ga = ((const float4*)gamma)[l16];
        float4 be = ((const float4*)beta)[l16];
        float m;
        m = s.x * invN; sc.x = ga.x * rsqrtf(q.x * invN - m * m + 1e-5f); sh.x = be.x - m * sc.x;
        m = s.y * invN; sc.y = ga.y * rsqrtf(q.y * invN - m * m + 1e-5f); sh.y = be.y - m * sc.y;
        m = s.z * invN; sc.z = ga.z * rsqrtf(q.z * invN - m * m + 1e-5f); sh.z = be.z - m * sc.z;
        m = s.w * invN; sc.w = ga.w * rsqrtf(q.w * invN - m * m + 1e-5f); sh.w = be.w - m * sc.w;
    }

#define LOADROW(IDX, V)                                                      \
    {                                                                        \
        ushort4 uv = *(const ushort4*)(x16 + (size_t)(IDX) * 64 + l16 * 4);  \
        V.x = h2f(uv.x); V.y = h2f(uv.y); V.z = h2f(uv.z); V.w = h2f(uv.w);  \
        if (DOBN) {                                                          \
            V.x = fmaxf(fmaf(V.x, sc.x, sh.x), 0.f);                         \
            V.y = fmaxf(fmaf(V.y, sc.y, sh.y), 0.f);                         \
            V.z = fmaxf(fmaf(V.z, sc.z, sh.z), 0.f);                         \
            V.w = fmaxf(fmaf(V.w, sc.w, sh.w), 0.f);                         \
        }                                                                    \
    }

    float4 acc = f4zero();
    {
        float4 v;
        LOADROW(n, v)
        if (grp == 0) acc = v;
    }

    int lo = rowptr[n], hi = rowptr[n + 1];
    int e = lo;
    for (; e + 8 <= hi; e += 8) {
        int i0 = col[e + grp];
        int i1 = col[e + 4 + grp];
        float4 v0, v1;
        LOADROW(i0, v0)
        LOADROW(i1, v1)
        acc.x += v0.x + v1.x; acc.y += v0.y + v1.y;
        acc.z += v0.z + v1.z; acc.w += v0.w + v1.w;
    }
    for (; e < hi; e += 4) {
        int ee = e + grp;
        bool ok = ee < hi;
        int idx = col[ok ? ee : (hi - 1)];
        float4 v;
        LOADROW(idx, v)
        if (ok) {
            acc.x += v.x; acc.y += v.y; acc.z += v.z; acc.w += v.w;
        }
    }
#undef LOADROW

    acc.x += __shfl_xor(acc.x, 16, 64); acc.y += __shfl_xor(acc.y, 16, 64);
    acc.z += __shfl_xor(acc.z, 16, 64); acc.w += __shfl_xor(acc.w, 16, 64);
    acc.x += __shfl_xor(acc.x, 32, 64); acc.y += __shfl_xor(acc.y, 32, 64);
    acc.z += __shfl_xor(acc.z, 32, 64); acc.w += __shfl_xor(acc.w, 32, 64);

    if (lane < 16) {
        ushort4 o;
        o.x = f2h(acc.x); o.y = f2h(acc.y); o.z = f2h(acc.z); o.w = f2h(acc.w);
        *(ushort4*)(hout + (size_t)n * 64 + l16 * 4) = o;
    }
}

// ---------------- MFMA 2-layer MLP: fp16 I/O, split bf16 hi/lo (exact for fp16 inputs) ----------------
// 16x16x32 bf16 MFMA. A: row=l&15, k=(l>>4)*8+j ; B: col=l&15, same k ;
// D: col=l&15, row=(l>>4)*4+reg.
__global__ __launch_bounds__(256, 5) void k_mlp(const unsigned short* __restrict__ h_in,
                                                unsigned short* __restrict__ h_out,
                                                const unsigned short* __restrict__ wt1,
                                                const float* __restrict__ b1,
                                                const unsigned short* __restrict__ wt2,
                                                const float* __restrict__ b2,
                                                float* __restrict__ pstat,
                                                int nNodes) {
    __shared__ __align__(16) unsigned short smem16[16384];   // 32KB
    unsigned short* sA_hi = smem16;            // [64][64] bf16 swz (A, then h1)
    unsigned short* sA_lo = smem16 + 4096;
    unsigned short* sW_hi = smem16 + 8192;     // W^T tile hi (W1, then W2)
    unsigned short* sW_lo = smem16 + 12288;    // W^T tile lo

    int tid = threadIdx.x;
    int n0 = blockIdx.x * 64;
    int lane = tid & 63;
    int w = tid >> 6;
    int lr = lane & 15;
    int q = lane >> 4;
    int r0 = w * 16;

    // --- prefetch FULL W2^T (hi+lo = 1024 uint4) into registers ---
    uint4 w2r[4];
#pragma unroll
    for (int it = 0; it < 4; ++it) w2r[it] = ((const uint4*)wt2)[it * 256 + tid];

    // --- stage A: fp16 h rows -> hi/lo bf16 (exact split), swizzled 16B chunks ---
#pragma unroll
    for (int it = 0; it < 2; ++it) {
        int idx = it * 256 + tid;           // 512 chunks of 8 halves (16B)
        int row = idx >> 3, ch = idx & 7;
        u16x8 iv = (u16x8)(0);
        if (n0 + row < nNodes)
            iv = *(const u16x8*)(h_in + (size_t)(n0 + row) * 64 + ch * 8);
        u16x8 hv, lv;
#pragma unroll
        for (int j = 0; j < 8; ++j) {
            float f = h2f(iv[j]);
            unsigned short h = f2bf(f);
            hv[j] = h;
            lv[j] = f2bf(f - bf2f(h));
        }
        int off = row * 64 + ((ch ^ (row & 7)) << 3);
        *(u16x8*)(sA_hi + off) = hv;
        *(u16x8*)(sA_lo + off) = lv;
    }
    // --- copy FULL W1^T hi/lo (1024 uint4) ---
    {
        uint4* d = (uint4*)sW_hi;
        const uint4* s = (const uint4*)wt1;
#pragma unroll
        for (int it = 0; it < 4; ++it) d[it * 256 + tid] = s[it * 256 + tid];
    }
    __syncthreads();

    f32x4 acc[4];

#define GEMM_SPLIT(BIAS)                                                         \
    {                                                                            \
        int rowA = r0 + lr;                                                      \
        const unsigned short* pah = sA_hi + rowA * 64;                           \
        const unsigned short* pal = sA_lo + rowA * 64;                           \
        int sr = rowA & 7;                                                       \
        bf16x8 ah0 = *(const bf16x8*)(pah + ((q ^ sr) << 3));                    \
        bf16x8 ah1 = *(const bf16x8*)(pah + (((4 + q) ^ sr) << 3));              \
        bf16x8 al0 = *(const bf16x8*)(pal + ((q ^ sr) << 3));                    \
        bf16x8 al1 = *(const bf16x8*)(pal + (((4 + q) ^ sr) << 3));              \
        _Pragma("unroll")                                                        \
        for (int ct = 0; ct < 4; ++ct) {                                         \
            int f = ct * 16 + lr;                                                \
            const unsigned short* pbh = sW_hi + f * 64;                          \
            const unsigned short* pbl = sW_lo + f * 64;                          \
            int sf = f & 7;                                                      \
            bf16x8 bh0 = *(const bf16x8*)(pbh + ((q ^ sf) << 3));                \
            bf16x8 bh1 = *(const bf16x8*)(pbh + (((4 + q) ^ sf) << 3));          \
            bf16x8 bl0 = *(const bf16x8*)(pbl + ((q ^ sf) << 3));                \
            bf16x8 bl1 = *(const bf16x8*)(pbl + (((4 + q) ^ sf) << 3));          \
            float bias = BIAS[f];                                                \
            f32x4 c = {bias, bias, bias, bias};                                  \
            c = __builtin_amdgcn_mfma_f32_16x16x32_bf16(al0, bh0, c, 0, 0, 0);   \
            c = __builtin_amdgcn_mfma_f32_16x16x32_bf16(al1, bh1, c, 0, 0, 0);   \
            c = __builtin_amdgcn_mfma_f32_16x16x32_bf16(ah0, bl0, c, 0, 0, 0);   \
            c = __builtin_amdgcn_mfma_f32_16x16x32_bf16(ah1, bl1, c, 0, 0, 0);   \
            c = __builtin_amdgcn_mfma_f32_16x16x32_bf16(ah0, bh0, c, 0, 0, 0);   \
            c = __builtin_amdgcn_mfma_f32_16x16x32_bf16(ah1, bh1, c, 0, 0, 0);   \
            acc[ct] = c;                                                         \
        }                                                                        \
    }

    // ---- GEMM1: h1 = relu(h @ W1 + b1) ----
    GEMM_SPLIT(b1)

    __syncthreads();   // all GEMM1 LDS reads done; sA & sW reusable

    // h1 -> sA region hi/lo; W2 regs (full hi+lo) -> sW
#pragma unroll
    for (int ct = 0; ct < 4; ++ct) {
        int f = ct * 16 + lr;
#pragma unroll
        for (int rg = 0; rg < 4; ++rg) {
            int row = r0 + q * 4 + rg;
            float v = fmaxf(acc[ct][rg], 0.f);
            unsigned short h = f2bf(v);
            int ix = swz_idx(row, f);
            sA_hi[ix] = h;
            sA_lo[ix] = f2bf(v - bf2f(h));
        }
    }
    {
        uint4* d = (uint4*)sW_hi;
#pragma unroll
        for (int it = 0; it < 4; ++it) d[it * 256 + tid] = w2r[it];
    }
    __syncthreads();

    // ---- GEMM2: out = relu(h1 @ W2 + b2) ----
    GEMM_SPLIT(b2)

    __syncthreads();   // all GEMM2 LDS reads done; sW reusable as stats scratch
#undef GEMM_SPLIT

    float* sS = (float*)sW_hi;     // [4][64] sums
    float* sQ = sS + 256;          // [4][64] sumsq

    // epilogue: relu -> fp16 global store + register stats (from the fp16-rounded values)
#pragma unroll
    for (int ct = 0; ct < 4; ++ct) {
        int f = ct * 16 + lr;
        float sp = 0.f, qp = 0.f;
#pragma unroll
        for (int rg = 0; rg < 4; ++rg) {
            int row = r0 + q * 4 + rg;
            float v = fmaxf(acc[ct][rg], 0.f);
            if (n0 + row < nNodes) {
                unsigned short hv = f2h(v);
                h_out[(size_t)(n0 + row) * 64 + f] = hv;
                float vq = h2f(hv);
                sp += vq;
                qp += vq * vq;
            }
        }
        sp += __shfl_xor(sp, 16, 64); qp += __shfl_xor(qp, 16, 64);
        sp += __shfl_xor(sp, 32, 64); qp += __shfl_xor(qp, 32, 64);
        if (q == 0) {
            sS[w * 64 + f] = sp;
            sQ[w * 64 + f] = qp;
        }
    }
    __syncthreads();
    // atomic-free: one contiguous 512B partial record per block
    if (tid < 128) {
        float v;
        if (tid < 64)
            v = sS[tid] + sS[64 + tid] + sS[128 + tid] + sS[192 + tid];
        else {
            int f = tid - 64;
            v = sQ[f] + sQ[64 + f] + sQ[128 + f] + sQ[192 + f];
        }
        pstat[(size_t)blockIdx.x * 128 + tid] = v;
    }
}

// ---------------- pooling (BN3 fused, fp16 in) + final GEMV ----------------
__device__ __forceinline__ int lower_bound_dev(const int* a, int n, int key) {
    int lo = 0, hi = n;
    while (lo < hi) {
        int mid = (lo + hi) >> 1;
        if (a[mid] < key) lo = mid + 1; else hi = mid;
    }
    return lo;
}

__global__ __launch_bounds__(256) void k_pool(const unsigned short* __restrict__ x16,
                                              const int* __restrict__ batch,
                                              const float* __restrict__ stats,
                                              const float* __restrict__ gamma,
                                              const float* __restrict__ beta,
                                              const float* __restrict__ Wf,
                                              const float* __restrict__ bf,
                                              float* __restrict__ out,
                                              int nNodes, float invN) {
    int wid = threadIdx.x >> 6;
    int lane = threadIdx.x & 63;
    int grp = lane >> 4;
    int l16 = lane & 15;
    int g = blockIdx.x * 4 + wid;

    float4 sc, sh;
    {
        float4 s  = ((const float4*)stats)[l16];
        float4 q  = ((const float4*)stats)[16 + l16];
        float4 ga = ((const float4*)gamma)[l16];
        float4 be = ((const float4*)beta)[l16];
        float m;
        m = s.x * invN; sc.x = ga.x * rsqrtf(q.x * invN - m * m + 1e-5f); sh.x = be.x - m * sc.x;
        m = s.y * invN; sc.y = ga.y * rsqrtf(q.y * invN - m * m + 1e-5f); sh.y = be.y - m * sc.y;
        m = s.z * invN; sc.z = ga.z * rsqrtf(q.z * invN - m * m + 1e-5f); sh.z = be.z - m * sc.z;
        m = s.w * invN; sc.w = ga.w * rsqrtf(q.w * invN - m * m + 1e-5f); sh.w = be.w - m * sc.w;
    }

    int lo = lower_bound_dev(batch, nNodes, g);
    int hi = lower_bound_dev(batch, nNodes, g + 1);

    float4 acc = f4zero();
    for (int r = lo + grp; r < hi; r += 4) {
        ushort4 uv = *(const ushort4*)(x16 + (size_t)r * 64 + l16 * 4);
        acc.x += fmaxf(fmaf(h2f(uv.x), sc.x, sh.x), 0.f);
        acc.y += fmaxf(fmaf(h2f(uv.y), sc.y, sh.y), 0.f);
        acc.z += fmaxf(fmaf(h2f(uv.z), sc.z, sh.z), 0.f);
        acc.w += fmaxf(fmaf(h2f(uv.w), sc.w, sh.w), 0.f);
    }
    acc.x += __shfl_xor(acc.x, 16, 64); acc.y += __shfl_xor(acc.y, 16, 64);
    acc.z += __shfl_xor(acc.z, 16, 64); acc.w += __shfl_xor(acc.w, 16, 64);
    acc.x += __shfl_xor(acc.x, 32, 64); acc.y += __shfl_xor(acc.y, 32, 64);
    acc.z += __shfl_xor(acc.z, 32, 64); acc.w += __shfl_xor(acc.w, 32, 64);

    float4 wf = ((const float4*)Wf)[l16];
    float p = acc.x * wf.x + acc.y * wf.y + acc.z * wf.z + acc.w * wf.w;
    p += __shfl_xor(p, 1, 64);
    p += __shfl_xor(p, 2, 64);
    p += __shfl_xor(p, 4, 64);
    p += __shfl_xor(p, 8, 64);
    if (lane == 0) out[g] = p + bf[0];
}

extern "C" void kernel_launch(void* const* d_in, const int* in_sizes, int n_in,
                              void* d_out, int out_size, void* d_ws, size_t ws_size,
                              hipStream_t stream) {
    const float* x_in  = (const float*)d_in[0];
    const int*   ei    = (const int*)d_in[1];
    const int*   batch = (const int*)d_in[2];
    const float* W1    = (const float*)d_in[3];
    const float* b1    = (const float*)d_in[4];
    const float* W2    = (const float*)d_in[5];
    const float* b2    = (const float*)d_in[6];
    const float* gamma = (const float*)d_in[7];
    const float* beta  = (const float*)d_in[8];
    const float* Wf    = (const float*)d_in[9];
    const float* bf    = (const float*)d_in[10];

    const int nNodes = in_sizes[0] / HIDDEN_C;   // 50000 (pack assumes <= 65536)
    const int nE = in_sizes[1] / 2;              // 800000
    const int* src = ei;
    const int* dst = ei + nE;

    const int nBuckets = (nNodes + 63) / 64;         // 782
    const int nTot = nBuckets * NCHUNK;              // 200192
    const int chunkSz = (nE + NCHUNK - 1) / NCHUNK;  // 3125
    const int scanBlocks = (nTot + 1023) / 1024;     // 196 (<=256)
    const float invN = 1.f / (float)nNodes;

    const size_t NH = ((size_t)nNodes * HIDDEN_C * sizeof(unsigned short) + 255) & ~(size_t)255;  // 6.4MB
    char* ws = (char*)d_ws;
    unsigned short* x16 = (unsigned short*)ws;               // fp16 input mirror
    unsigned short* hA  = (unsigned short*)(ws + NH);
    unsigned short* hB  = (unsigned short*)(ws + 2 * NH);
    float*    stats   = (float*)(ws + 3 * NH);               // 3 x 128 floats
    unsigned short* wtbuf = (unsigned short*)(ws + 3 * NH + 4096);   // 96KB
    float*    pstat   = (float*)(ws + 3 * NH + 4096 + 98304);        // 400KB
    int*      rowptr  = (int*)((char*)pstat + 409600);       // nNodes+1
    int*      partial = rowptr + nNodes + 64;                // 256
    int*      col     = partial + 256;                       // nE
    // transient CSR-build scratch aliased into hB (hB first written at layer-1 agg)
    unsigned* ebuf    = (unsigned*)hB;                       // nE (3.2MB)
    int*      cnt     = (int*)((char*)hB + (size_t)nE * 4);  // nTot (0.8MB)
    int*      eoff    = cnt + nTot + 64;                     // nTot (0.8MB)

    const int mlpGrid = nBuckets;                            // 782 (64-row tiles)
    const int aggGrid = (nNodes + 3) / 4;
    const int cvtGrid = (nNodes * 16 + 255) / 256;           // float4 groups

    // ---- input cvt + weight prep (once) + CSR build ----
    k_xcvt<<<cvtGrid, 256, 0, stream>>>((const float4*)x_in, (ushort4*)x16, nNodes * 16);
    k_wprep<<<6, 256, 0, stream>>>(W1, W2, wtbuf);
    k_bcount<<<NCHUNK, 256, 0, stream>>>(dst, cnt, nE, chunkSz, nBuckets);
    k_blocksum<<<scanBlocks, 256, 0, stream>>>(cnt, partial, nTot);
    k_scanpartial<<<1, 256, 0, stream>>>(partial, rowptr + nNodes, scanBlocks, nE);
    k_writeptr<<<scanBlocks, 256, 0, stream>>>(cnt, partial, eoff, nTot);
    k_bscatter<<<NCHUNK, 256, 0, stream>>>(src, dst, eoff, ebuf, nE, chunkSz, nBuckets);
    k_bfill<<<nBuckets, 256, 0, stream>>>(ebuf, eoff, rowptr, col, nNodes, nE, nBuckets);

    // ---- 3 layers: agg (fp16 I/O) + MFMA MLP (fp16 I/O, split bf16) + statred ----
    const unsigned short* prev_h = x16;
    unsigned short* cur = hA;
    for (int i = 0; i < 3; ++i) {
        if (i == 0) {
            k_aggbn<false><<<aggGrid, 256, 0, stream>>>(prev_h, rowptr, col,
                                                        nullptr, nullptr, nullptr,
                                                        cur, nNodes, invN);
        } else {
            k_aggbn<true><<<aggGrid, 256, 0, stream>>>(prev_h, rowptr, col,
                                                       stats + (size_t)(i - 1) * 128,
                                                       gamma + (size_t)(i - 1) * 64,
                                                       beta + (size_t)(i - 1) * 64,
                                                       cur, nNodes, invN);
        }
        k_mlp<<<mlpGrid, 256, 0, stream>>>(cur, cur,
                                           wtbuf + (size_t)(2 * i) * 8192, b1 + (size_t)i * 64,
                                           wtbuf + (size_t)(2 * i + 1) * 8192, b2 + (size_t)i * 64,
                                           pstat, nNodes);
        k_statred<<<128, 256, 0, stream>>>(pstat, stats + (size_t)i * 128, nBuckets);
        prev_h = cur;
        cur = (cur == hA) ? hB : hA;
    }

    k_pool<<<64, 256, 0, stream>>>(prev_h, batch, stats + 256, gamma + 128, beta + 128,
                                   Wf, bf, (float*)d_out, nNodes, invN);
}

// Round 18
// 196.372 us; speedup vs baseline: 1.2819x; 1.0283x over previous
//
#include <hip/hip_runtime.h>

#define HIDDEN_C 64
#define NCHUNK 256

typedef __attribute__((ext_vector_type(8))) short bf16x8;
typedef __attribute__((ext_vector_type(8))) unsigned short u16x8;
typedef __attribute__((ext_vector_type(4))) float f32x4;

__device__ __forceinline__ float4 f4zero() { return make_float4(0.f, 0.f, 0.f, 0.f); }

__device__ __forceinline__ unsigned short f2bf(float f) {
    unsigned u = __float_as_uint(f);
    u += 0x7FFF + ((u >> 16) & 1);          // round-to-nearest-even
    return (unsigned short)(u >> 16);
}
__device__ __forceinline__ float bf2f(unsigned short h) {
    return __uint_as_float(((unsigned)h) << 16);
}
__device__ __forceinline__ unsigned short f2h(float f) {
    _Float16 h = (_Float16)f;
    unsigned short u;
    __builtin_memcpy(&u, &h, 2);
    return u;
}
__device__ __forceinline__ float h2f(unsigned short u) {
    _Float16 h;
    __builtin_memcpy(&h, &u, 2);
    return (float)h;
}

// swizzled u16 index within a [rows][64 k] bf16 tile (128B rows, 16B-chunk XOR)
__device__ __forceinline__ int swz_idx(int row, int k) {
    return row * 64 + ((((k >> 3) ^ (row & 7)) << 3) | (k & 7));
}

// ---------------- fp32 -> fp16 input conversion (once) ----------------
__global__ __launch_bounds__(256) void k_xcvt(const float4* __restrict__ in,
                                              ushort4* __restrict__ out, int n4) {
    int i = blockIdx.x * 256 + threadIdx.x;
    if (i < n4) {
        float4 v = in[i];
        ushort4 o;
        o.x = f2h(v.x); o.y = f2h(v.y); o.z = f2h(v.z); o.w = f2h(v.w);
        out[i] = o;
    }
}

// ---------------- generic exclusive scan ----------------
__global__ __launch_bounds__(256) void k_blocksum(const int* __restrict__ deg,
                                                  int* __restrict__ partial, int n) {
    int base = blockIdx.x * 1024 + threadIdx.x * 4;
    int s = 0;
#pragma unroll
    for (int k = 0; k < 4; ++k) {
        int i = base + k;
        if (i < n) s += deg[i];
    }
    __shared__ int red[256];
    red[threadIdx.x] = s;
    __syncthreads();
    for (int d = 128; d > 0; d >>= 1) {
        if (threadIdx.x < d) red[threadIdx.x] += red[threadIdx.x + d];
        __syncthreads();
    }
    if (threadIdx.x == 0) partial[blockIdx.x] = red[0];
}

__global__ __launch_bounds__(256) void k_scanpartial(int* __restrict__ partial,
                                                     int* __restrict__ last_slot,
                                                     int nBlocks, int nE) {
    __shared__ int buf[256];
    int tid = threadIdx.x;
    int v = (tid < nBlocks) ? partial[tid] : 0;
    buf[tid] = v;
    __syncthreads();
    for (int d = 1; d < 256; d <<= 1) {
        int t = (tid >= d) ? buf[tid - d] : 0;
        __syncthreads();
        buf[tid] += t;
        __syncthreads();
    }
    if (tid < nBlocks) partial[tid] = buf[tid] - v;
    if (tid == 0) last_slot[0] = nE;
}

__global__ __launch_bounds__(256) void k_writeptr(const int* __restrict__ deg,
                                                  const int* __restrict__ partial,
                                                  int* __restrict__ outp, int n) {
    int tid = threadIdx.x;
    int base = blockIdx.x * 1024 + tid * 4;
    int d[4];
    int s = 0;
#pragma unroll
    for (int k = 0; k < 4; ++k) {
        int i = base + k;
        d[k] = (i < n) ? deg[i] : 0;
        s += d[k];
    }
    __shared__ int buf[256];
    buf[tid] = s;
    __syncthreads();
    for (int dd = 1; dd < 256; dd <<= 1) {
        int t = (tid >= dd) ? buf[tid - dd] : 0;
        __syncthreads();
        buf[tid] += t;
        __syncthreads();
    }
    int off = partial[blockIdx.x] + buf[tid] - s;
#pragma unroll
    for (int k = 0; k < 4; ++k) {
        int i = base + k;
        if (i < n) {
            outp[i] = off;
            off += d[k];
        }
    }
}

// ---------------- bucket partition (bucket = dst>>6) ----------------
__global__ __launch_bounds__(256) void k_bcount(const int* __restrict__ dst,
                                                int* __restrict__ cnt,
                                                int nE, int chunkSz, int nBuckets) {
    __shared__ int h[1024];
    int c = blockIdx.x, tid = threadIdx.x;
    for (int i = tid; i < nBuckets; i += 256) h[i] = 0;
    __syncthreads();
    int beg = c * chunkSz;
    int end = beg + chunkSz; if (end > nE) end = nE;
    int e = beg + tid;
    for (; e + 256 < end; e += 512) {
        int d0 = dst[e];
        int d1 = dst[e + 256];
        atomicAdd(&h[d0 >> 6], 1);
        atomicAdd(&h[d1 >> 6], 1);
    }
    if (e < end) atomicAdd(&h[dst[e] >> 6], 1);
    __syncthreads();
    for (int i = tid; i < nBuckets; i += 256) cnt[i * NCHUNK + c] = h[i];
}

__global__ __launch_bounds__(256) void k_bscatter(const int* __restrict__ src,
                                                  const int* __restrict__ dst,
                                                  const int* __restrict__ eoff,
                                                  unsigned* __restrict__ ebuf,
                                                  int nE, int chunkSz, int nBuckets) {
    __shared__ int cur[1024];
    int c = blockIdx.x, tid = threadIdx.x;
    for (int i = tid; i < nBuckets; i += 256) cur[i] = eoff[i * NCHUNK + c];
    __syncthreads();
    int beg = c * chunkSz;
    int end = beg + chunkSz; if (end > nE) end = nE;
    int e = beg + tid;
    for (; e + 256 < end; e += 512) {
        int d0 = dst[e];
        int d1 = dst[e + 256];
        int s0 = src[e];
        int s1 = src[e + 256];
        int p0 = atomicAdd(&cur[d0 >> 6], 1);
        int p1 = atomicAdd(&cur[d1 >> 6], 1);
        ebuf[p0] = ((unsigned)(d0 & 63) << 16) | (unsigned)s0;  // nNodes<=65536
        ebuf[p1] = ((unsigned)(d1 & 63) << 16) | (unsigned)s1;
    }
    if (e < end) {
        int d = dst[e];
        int pos = atomicAdd(&cur[d >> 6], 1);
        ebuf[pos] = ((unsigned)(d & 63) << 16) | (unsigned)src[e];
    }
}

__global__ __launch_bounds__(256) void k_bfill(const unsigned* __restrict__ ebuf,
                                               const int* __restrict__ eoff,
                                               int* __restrict__ rowptr,
                                               int* __restrict__ col,
                                               int nNodes, int nE, int nBuckets) {
    __shared__ int deg[64], cur[64];
    int b = blockIdx.x, tid = threadIdx.x;
    int lo = eoff[b * NCHUNK];
    int hi = (b + 1 < nBuckets) ? eoff[(b + 1) * NCHUNK] : nE;
    if (tid < 64) deg[tid] = 0;
    __syncthreads();
    for (int e = lo + tid; e < hi; e += 256) atomicAdd(&deg[ebuf[e] >> 16], 1);
    __syncthreads();
    if (tid < 64) {
        int d = deg[tid];
        int s = d;
        for (int o = 1; o < 64; o <<= 1) {
            int t = __shfl_up(s, o, 64);
            if (tid >= o) s += t;
        }
        int st = s - d;
        cur[tid] = lo + st;
        int node = b * 64 + tid;
        if (node < nNodes) rowptr[node] = lo + st;
    }
    __syncthreads();
    for (int e = lo + tid; e < hi; e += 256) {
        unsigned pk = ebuf[e];
        int pos = atomicAdd(&cur[pk >> 16], 1);
        col[pos] = (int)(pk & 0xFFFFu);
    }
}

// ---------------- weight prep: W[k][f] fp32 -> W^T hi/lo bf16 swizzled tiles ----------------
__global__ __launch_bounds__(256) void k_wprep(const float* __restrict__ W1,
                                               const float* __restrict__ W2,
                                               unsigned short* __restrict__ wt) {
    __shared__ unsigned short s[8192];
    int b = blockIdx.x;
    int layer = b >> 1;
    const float* src = ((b & 1) ? W2 : W1) + (size_t)layer * 4096;
    int tid = threadIdx.x;
    int k = tid >> 2;
    int f0 = (tid & 3) * 16;
    const float* srcp = src + k * 64 + f0;
#pragma unroll
    for (int j4 = 0; j4 < 4; ++j4) {
        float4 wv = *(const float4*)(srcp + j4 * 4);
        float c[4] = {wv.x, wv.y, wv.z, wv.w};
        int f = f0 + j4 * 4;
#pragma unroll
        for (int j = 0; j < 4; ++j) {
            unsigned short h = f2bf(c[j]);
            int ix = swz_idx(f + j, k);
            s[ix] = h;
            s[4096 + ix] = f2bf(c[j] - bf2f(h));
        }
    }
    __syncthreads();
    uint4* dst = (uint4*)(wt + (size_t)b * 8192);
    const uint4* sp = (const uint4*)s;
#pragma unroll
    for (int it = 0; it < 4; ++it) dst[it * 256 + tid] = sp[it * 256 + tid];
}

// ---------------- per-stat reduction of block partials ----------------
__global__ __launch_bounds__(256) void k_statred(const float* __restrict__ pstat,
                                                 float* __restrict__ stats, int nb) {
    int j = blockIdx.x;
    int tid = threadIdx.x;
    float s = 0.f;
    for (int b = tid; b < nb; b += 256) s += pstat[(size_t)b * 128 + j];
    __shared__ float red[256];
    red[tid] = s;
    __syncthreads();
    for (int d = 128; d > 0; d >>= 1) {
        if (tid < d) red[tid] += red[tid + d];
        __syncthreads();
    }
    if (tid == 0) stats[j] = red[0];
}

// ---------------- fused BN(prev) + gather (fp16, 8 groups x 8 lanes x 16B) ----------------
// one load instruction fetches 8 neighbor rows; main loop 16 edges/iter (2 indep loads)
template <bool DOBN>
__global__ __launch_bounds__(256) void k_aggbn(const unsigned short* __restrict__ x16,
                                               const int* __restrict__ rowptr,
                                               const int* __restrict__ col,
                                               const float* __restrict__ stats,
                                               const float* __restrict__ gamma,
                                               const float* __restrict__ beta,
                                               unsigned short* __restrict__ hout,
                                               int nNodes, float invN) {
    int wid = threadIdx.x >> 6;
    int lane = threadIdx.x & 63;
    int g8 = lane >> 3;        // edge group 0..7
    int l8 = lane & 7;         // feature chunk of 8
    int n = blockIdx.x * 4 + wid;
    if (n >= nNodes) return;

    float sc[8], sh[8];
    if (DOBN) {
#pragma unroll
        for (int j = 0; j < 8; ++j) {
            int f = l8 * 8 + j;
            float m = stats[f] * invN;
            float var = stats[64 + f] * invN - m * m;
            sc[j] = gamma[f] * rsqrtf(var + 1e-5f);
            sh[j] = beta[f] - m * sc[j];
        }
    }

#define LOADROW8(IDX, OP)                                                    \
    {                                                                        \
        u16x8 uv = *(const u16x8*)(x16 + (size_t)(IDX) * 64 + l8 * 8);       \
        _Pragma("unroll")                                                    \
        for (int j = 0; j < 8; ++j) {                                        \
            float v = h2f(uv[j]);                                            \
            if (DOBN) v = fmaxf(fmaf(v, sc[j], sh[j]), 0.f);                 \
            OP;                                                              \
        }                                                                    \
    }

    float acc[8] = {0.f, 0.f, 0.f, 0.f, 0.f, 0.f, 0.f, 0.f};
    if (g8 == 0) {
        LOADROW8(n, acc[j] = v)
    }

    int lo = rowptr[n], hi = rowptr[n + 1];
    int e = lo;
    for (; e + 16 <= hi; e += 16) {
        int i0 = col[e + g8];
        int i1 = col[e + 8 + g8];
        float t[8];
        LOADROW8(i0, t[j] = v)
        LOADROW8(i1, t[j] += v)
#pragma unroll
        for (int j = 0; j < 8; ++j) acc[j] += t[j];
    }
    for (; e + 8 <= hi; e += 8) {
        int i0 = col[e + g8];
        LOADROW8(i0, acc[j] += v)
    }
    if (e < hi) {
        int ee = e + g8;
        bool ok = ee < hi;
        int idx = col[ok ? ee : (hi - 1)];
        float t[8];
        LOADROW8(idx, t[j] = v)
        if (ok) {
#pragma unroll
            for (int j = 0; j < 8; ++j) acc[j] += t[j];
        }
    }
#undef LOADROW8

#pragma unroll
    for (int j = 0; j < 8; ++j) {
        acc[j] += __shfl_xor(acc[j], 8, 64);
        acc[j] += __shfl_xor(acc[j], 16, 64);
        acc[j] += __shfl_xor(acc[j], 32, 64);
    }

    if (lane < 8) {
        u16x8 o;
#pragma unroll
        for (int j = 0; j < 8; ++j) o[j] = f2h(acc[j]);
        *(u16x8*)(hout + (size_t)n * 64 + lane * 8) = o;
    }
}

// ---------------- MFMA 2-layer MLP: fp16 I/O, split bf16 hi/lo ----------------
__global__ __launch_bounds__(256, 5) void k_mlp(const unsigned short* __restrict__ h_in,
                                                unsigned short* __restrict__ h_out,
                                                const unsigned short* __restrict__ wt1,
                                                const float* __restrict__ b1,
                                                const unsigned short* __restrict__ wt2,
                                                const float* __restrict__ b2,
                                                float* __restrict__ pstat,
                                                int nNodes) {
    __shared__ __align__(16) unsigned short smem16[16384];   // 32KB
    unsigned short* sA_hi = smem16;
    unsigned short* sA_lo = smem16 + 4096;
    unsigned short* sW_hi = smem16 + 8192;
    unsigned short* sW_lo = smem16 + 12288;

    int tid = threadIdx.x;
    int n0 = blockIdx.x * 64;
    int lane = tid & 63;
    int w = tid >> 6;
    int lr = lane & 15;
    int q = lane >> 4;
    int r0 = w * 16;

    uint4 w2r[4];
#pragma unroll
    for (int it = 0; it < 4; ++it) w2r[it] = ((const uint4*)wt2)[it * 256 + tid];

#pragma unroll
    for (int it = 0; it < 2; ++it) {
        int idx = it * 256 + tid;
        int row = idx >> 3, ch = idx & 7;
        u16x8 iv = (u16x8)(0);
        if (n0 + row < nNodes)
            iv = *(const u16x8*)(h_in + (size_t)(n0 + row) * 64 + ch * 8);
        u16x8 hv, lv;
#pragma unroll
        for (int j = 0; j < 8; ++j) {
            float f = h2f(iv[j]);
            unsigned short h = f2bf(f);
            hv[j] = h;
            lv[j] = f2bf(f - bf2f(h));
        }
        int off = row * 64 + ((ch ^ (row & 7)) << 3);
        *(u16x8*)(sA_hi + off) = hv;
        *(u16x8*)(sA_lo + off) = lv;
    }
    {
        uint4* d = (uint4*)sW_hi;
        const uint4* s = (const uint4*)wt1;
#pragma unroll
        for (int it = 0; it < 4; ++it) d[it * 256 + tid] = s[it * 256 + tid];
    }
    __syncthreads();

    f32x4 acc[4];

#define GEMM_SPLIT(BIAS)                                                         \
    {                                                                            \
        int rowA = r0 + lr;                                                      \
        const unsigned short* pah = sA_hi + rowA * 64;                           \
        const unsigned short* pal = sA_lo + rowA * 64;                           \
        int sr = rowA & 7;                                                       \
        bf16x8 ah0 = *(const bf16x8*)(pah + ((q ^ sr) << 3));                    \
        bf16x8 ah1 = *(const bf16x8*)(pah + (((4 + q) ^ sr) << 3));              \
        bf16x8 al0 = *(const bf16x8*)(pal + ((q ^ sr) << 3));                    \
        bf16x8 al1 = *(const bf16x8*)(pal + (((4 + q) ^ sr) << 3));              \
        _Pragma("unroll")                                                        \
        for (int ct = 0; ct < 4; ++ct) {                                         \
            int f = ct * 16 + lr;                                                \
            const unsigned short* pbh = sW_hi + f * 64;                          \
            const unsigned short* pbl = sW_lo + f * 64;                          \
            int sf = f & 7;                                                      \
            bf16x8 bh0 = *(const bf16x8*)(pbh + ((q ^ sf) << 3));                \
            bf16x8 bh1 = *(const bf16x8*)(pbh + (((4 + q) ^ sf) << 3));          \
            bf16x8 bl0 = *(const bf16x8*)(pbl + ((q ^ sf) << 3));                \
            bf16x8 bl1 = *(const bf16x8*)(pbl + (((4 + q) ^ sf) << 3));          \
            float bias = BIAS[f];                                                \
            f32x4 c = {bias, bias, bias, bias};                                  \
            c = __builtin_amdgcn_mfma_f32_16x16x32_bf16(al0, bh0, c, 0, 0, 0);   \
            c = __builtin_amdgcn_mfma_f32_16x16x32_bf16(al1, bh1, c, 0, 0, 0);   \
            c = __builtin_amdgcn_mfma_f32_16x16x32_bf16(ah0, bl0, c, 0, 0, 0);   \
            c = __builtin_amdgcn_mfma_f32_16x16x32_bf16(ah1, bl1, c, 0, 0, 0);   \
            c = __builtin_amdgcn_mfma_f32_16x16x32_bf16(ah0, bh0, c, 0, 0, 0);   \
            c = __builtin_amdgcn_mfma_f32_16x16x32_bf16(ah1, bh1, c, 0, 0, 0);   \
            acc[ct] = c;                                                         \
        }                                                                        \
    }

    GEMM_SPLIT(b1)

    __syncthreads();

#pragma unroll
    for (int ct = 0; ct < 4; ++ct) {
        int f = ct * 16 + lr;
#pragma unroll
        for (int rg = 0; rg < 4; ++rg) {
            int row = r0 + q * 4 + rg;
            float v = fmaxf(acc[ct][rg], 0.f);
            unsigned short h = f2bf(v);
            int ix = swz_idx(row, f);
            sA_hi[ix] = h;
            sA_lo[ix] = f2bf(v - bf2f(h));
        }
    }
    {
        uint4* d = (uint4*)sW_hi;
#pragma unroll
        for (int it = 0; it < 4; ++it) d[it * 256 + tid] = w2r[it];
    }
    __syncthreads();

    GEMM_SPLIT(b2)

    __syncthreads();
#undef GEMM_SPLIT

    float* sS = (float*)sW_hi;
    float* sQ = sS + 256;

#pragma unroll
    for (int ct = 0; ct < 4; ++ct) {
        int f = ct * 16 + lr;
        float sp = 0.f, qp = 0.f;
#pragma unroll
        for (int rg = 0; rg < 4; ++rg) {
            int row = r0 + q * 4 + rg;
            float v = fmaxf(acc[ct][rg], 0.f);
            if (n0 + row < nNodes) {
                unsigned short hv = f2h(v);
                h_out[(size_t)(n0 + row) * 64 + f] = hv;
                float vq = h2f(hv);
                sp += vq;
                qp += vq * vq;
            }
        }
        sp += __shfl_xor(sp, 16, 64); qp += __shfl_xor(qp, 16, 64);
        sp += __shfl_xor(sp, 32, 64); qp += __shfl_xor(qp, 32, 64);
        if (q == 0) {
            sS[w * 64 + f] = sp;
            sQ[w * 64 + f] = qp;
        }
    }
    __syncthreads();
    if (tid < 128) {
        float v;
        if (tid < 64)
            v = sS[tid] + sS[64 + tid] + sS[128 + tid] + sS[192 + tid];
        else {
            int f = tid - 64;
            v = sQ[f] + sQ[64 + f] + sQ[128 + f] + sQ[192 + f];
        }
        pstat[(size_t)blockIdx.x * 128 + tid] = v;
    }
}

// ---------------- pooling (BN3 fused, fp16 in) + final GEMV ----------------
__device__ __forceinline__ int lower_bound_dev(const int* a, int n, int key) {
    int lo = 0, hi = n;
    while (lo < hi) {
        int mid = (lo + hi) >> 1;
        if (a[mid] < key) lo = mid + 1; else hi = mid;
    }
    return lo;
}

__global__ __launch_bounds__(256) void k_pool(const unsigned short* __restrict__ x16,
                                              const int* __restrict__ batch,
                                              const float* __restrict__ stats,
                                              const float* __restrict__ gamma,
                                              const float* __restrict__ beta,
                                              const float* __restrict__ Wf,
                                              const float* __restrict__ bf,
                                              float* __restrict__ out,
                                              int nNodes, float invN) {
    int wid = threadIdx.x >> 6;
    int lane = threadIdx.x & 63;
    int grp = lane >> 4;
    int l16 = lane & 15;
    int g = blockIdx.x * 4 + wid;

    float4 sc, sh;
    {
        float4 s  = ((const float4*)stats)[l16];
        float4 q  = ((const float4*)stats)[16 + l16];
        float4 ga = ((const float4*)gamma)[l16];
        float4 be = ((const float4*)beta)[l16];
        float m;
        m = s.x * invN; sc.x = ga.x * rsqrtf(q.x * invN - m * m + 1e-5f); sh.x = be.x - m * sc.x;
        m = s.y * invN; sc.y = ga.y * rsqrtf(q.y * invN - m * m + 1e-5f); sh.y = be.y - m * sc.y;
        m = s.z * invN; sc.z = ga.z * rsqrtf(q.z * invN - m * m + 1e-5f); sh.z = be.z - m * sc.z;
        m = s.w * invN; sc.w = ga.w * rsqrtf(q.w * invN - m * m + 1e-5f); sh.w = be.w - m * sc.w;
    }

    int lo = lower_bound_dev(batch, nNodes, g);
    int hi = lower_bound_dev(batch, nNodes, g + 1);

    float4 acc = f4zero();
    for (int r = lo + grp; r < hi; r += 4) {
        ushort4 uv = *(const ushort4*)(x16 + (size_t)r * 64 + l16 * 4);
        acc.x += fmaxf(fmaf(h2f(uv.x), sc.x, sh.x), 0.f);
        acc.y += fmaxf(fmaf(h2f(uv.y), sc.y, sh.y), 0.f);
        acc.z += fmaxf(fmaf(h2f(uv.z), sc.z, sh.z), 0.f);
        acc.w += fmaxf(fmaf(h2f(uv.w), sc.w, sh.w), 0.f);
    }
    acc.x += __shfl_xor(acc.x, 16, 64); acc.y += __shfl_xor(acc.y, 16, 64);
    acc.z += __shfl_xor(acc.z, 16, 64); acc.w += __shfl_xor(acc.w, 16, 64);
    acc.x += __shfl_xor(acc.x, 32, 64); acc.y += __shfl_xor(acc.y, 32, 64);
    acc.z += __shfl_xor(acc.z, 32, 64); acc.w += __shfl_xor(acc.w, 32, 64);

    float4 wf = ((const float4*)Wf)[l16];
    float p = acc.x * wf.x + acc.y * wf.y + acc.z * wf.z + acc.w * wf.w;
    p += __shfl_xor(p, 1, 64);
    p += __shfl_xor(p, 2, 64);
    p += __shfl_xor(p, 4, 64);
    p += __shfl_xor(p, 8, 64);
    if (lane == 0) out[g] = p + bf[0];
}

extern "C" void kernel_launch(void* const* d_in, const int* in_sizes, int n_in,
                              void* d_out, int out_size, void* d_ws, size_t ws_size,
                              hipStream_t stream) {
    const float* x_in  = (const float*)d_in[0];
    const int*   ei    = (const int*)d_in[1];
    const int*   batch = (const int*)d_in[2];
    const float* W1    = (const float*)d_in[3];
    const float* b1    = (const float*)d_in[4];
    const float* W2    = (const float*)d_in[5];
    const float* b2    = (const float*)d_in[6];
    const float* gamma = (const float*)d_in[7];
    const float* beta  = (const float*)d_in[8];
    const float* Wf    = (const float*)d_in[9];
    const float* bf    = (const float*)d_in[10];

    const int nNodes = in_sizes[0] / HIDDEN_C;   // 50000 (pack assumes <= 65536)
    const int nE = in_sizes[1] / 2;              // 800000
    const int* src = ei;
    const int* dst = ei + nE;

    const int nBuckets = (nNodes + 63) / 64;         // 782
    const int nTot = nBuckets * NCHUNK;              // 200192
    const int chunkSz = (nE + NCHUNK - 1) / NCHUNK;  // 3125
    const int scanBlocks = (nTot + 1023) / 1024;     // 196 (<=256)
    const float invN = 1.f / (float)nNodes;

    const size_t NH = ((size_t)nNodes * HIDDEN_C * sizeof(unsigned short) + 255) & ~(size_t)255;  // 6.4MB
    char* ws = (char*)d_ws;
    unsigned short* x16 = (unsigned short*)ws;
    unsigned short* hA  = (unsigned short*)(ws + NH);
    unsigned short* hB  = (unsigned short*)(ws + 2 * NH);
    float*    stats   = (float*)(ws + 3 * NH);
    unsigned short* wtbuf = (unsigned short*)(ws + 3 * NH + 4096);
    float*    pstat   = (float*)(ws + 3 * NH + 4096 + 98304);
    int*      rowptr  = (int*)((char*)pstat + 409600);
    int*      partial = rowptr + nNodes + 64;
    int*      col     = partial + 256;
    unsigned* ebuf    = (unsigned*)hB;
    int*      cnt     = (int*)((char*)hB + (size_t)nE * 4);
    int*      eoff    = cnt + nTot + 64;

    const int mlpGrid = nBuckets;
    const int aggGrid = (nNodes + 3) / 4;
    const int cvtGrid = (nNodes * 16 + 255) / 256;

    k_xcvt<<<cvtGrid, 256, 0, stream>>>((const float4*)x_in, (ushort4*)x16, nNodes * 16);
    k_wprep<<<6, 256, 0, stream>>>(W1, W2, wtbuf);
    k_bcount<<<NCHUNK, 256, 0, stream>>>(dst, cnt, nE, chunkSz, nBuckets);
    k_blocksum<<<scanBlocks, 256, 0, stream>>>(cnt, partial, nTot);
    k_scanpartial<<<1, 256, 0, stream>>>(partial, rowptr + nNodes, scanBlocks, nE);
    k_writeptr<<<scanBlocks, 256, 0, stream>>>(cnt, partial, eoff, nTot);
    k_bscatter<<<NCHUNK, 256, 0, stream>>>(src, dst, eoff, ebuf, nE, chunkSz, nBuckets);
    k_bfill<<<nBuckets, 256, 0, stream>>>(ebuf, eoff, rowptr, col, nNodes, nE, nBuckets);

    const unsigned short* prev_h = x16;
    unsigned short* cur = hA;
    for (int i = 0; i < 3; ++i) {
        if (i == 0) {
            k_aggbn<false><<<aggGrid, 256, 0, stream>>>(prev_h, rowptr, col,
                                                        nullptr, nullptr, nullptr,
                                                        cur, nNodes, invN);
        } else {
            k_aggbn<true><<<aggGrid, 256, 0, stream>>>(prev_h, rowptr, col,
                                                       stats + (size_t)(i - 1) * 128,
                                                       gamma + (size_t)(i - 1) * 64,
                                                       beta + (size_t)(i - 1) * 64,
                                                       cur, nNodes, invN);
        }
        k_mlp<<<mlpGrid, 256, 0, stream>>>(cur, cur,
                                           wtbuf + (size_t)(2 * i) * 8192, b1 + (size_t)i * 64,
                                           wtbuf + (size_t)(2 * i + 1) * 8192, b2 + (size_t)i * 64,
                                           pstat, nNodes);
        k_statred<<<128, 256, 0, stream>>>(pstat, stats + (size_t)i * 128, nBuckets);
        prev_h = cur;
        cur = (cur == hA) ? hB : hA;
    }

    k_pool<<<64, 256, 0, stream>>>(prev_h, batch, stats + 256, gamma + 128, beta + 128,
                                   Wf, bf, (float*)d_out, nNodes, invN);
}

// Round 19
// 195.266 us; speedup vs baseline: 1.2892x; 1.0057x over previous
//
#include <hip/hip_runtime.h>

#define HIDDEN_C 64
#define NCHUNK 256

typedef __attribute__((ext_vector_type(8))) short bf16x8;
typedef __attribute__((ext_vector_type(8))) unsigned short u16x8;
typedef __attribute__((ext_vector_type(4))) float f32x4;

__device__ __forceinline__ float4 f4zero() { return make_float4(0.f, 0.f, 0.f, 0.f); }

__device__ __forceinline__ unsigned short f2bf(float f) {
    unsigned u = __float_as_uint(f);
    u += 0x7FFF + ((u >> 16) & 1);          // round-to-nearest-even
    return (unsigned short)(u >> 16);
}
__device__ __forceinline__ float bf2f(unsigned short h) {
    return __uint_as_float(((unsigned)h) << 16);
}
__device__ __forceinline__ unsigned short f2h(float f) {
    _Float16 h = (_Float16)f;
    unsigned short u;
    __builtin_memcpy(&u, &h, 2);
    return u;
}
__device__ __forceinline__ float h2f(unsigned short u) {
    _Float16 h;
    __builtin_memcpy(&h, &u, 2);
    return (float)h;
}

// swizzled u16 index within a [rows][64 k] bf16 tile (128B rows, 16B-chunk XOR)
__device__ __forceinline__ int swz_idx(int row, int k) {
    return row * 64 + ((((k >> 3) ^ (row & 7)) << 3) | (k & 7));
}

// ---------------- fp32 -> fp16 input conversion (once) ----------------
__global__ __launch_bounds__(256) void k_xcvt(const float4* __restrict__ in,
                                              ushort4* __restrict__ out, int n4) {
    int i = blockIdx.x * 256 + threadIdx.x;
    if (i < n4) {
        float4 v = in[i];
        ushort4 o;
        o.x = f2h(v.x); o.y = f2h(v.y); o.z = f2h(v.z); o.w = f2h(v.w);
        out[i] = o;
    }
}

// ---------------- generic exclusive scan ----------------
__global__ __launch_bounds__(256) void k_blocksum(const int* __restrict__ deg,
                                                  int* __restrict__ partial, int n) {
    int base = blockIdx.x * 1024 + threadIdx.x * 4;
    int s = 0;
#pragma unroll
    for (int k = 0; k < 4; ++k) {
        int i = base + k;
        if (i < n) s += deg[i];
    }
    __shared__ int red[256];
    red[threadIdx.x] = s;
    __syncthreads();
    for (int d = 128; d > 0; d >>= 1) {
        if (threadIdx.x < d) red[threadIdx.x] += red[threadIdx.x + d];
        __syncthreads();
    }
    if (threadIdx.x == 0) partial[blockIdx.x] = red[0];
}

__global__ __launch_bounds__(256) void k_scanpartial(int* __restrict__ partial,
                                                     int* __restrict__ last_slot,
                                                     int nBlocks, int nE) {
    __shared__ int buf[256];
    int tid = threadIdx.x;
    int v = (tid < nBlocks) ? partial[tid] : 0;
    buf[tid] = v;
    __syncthreads();
    for (int d = 1; d < 256; d <<= 1) {
        int t = (tid >= d) ? buf[tid - d] : 0;
        __syncthreads();
        buf[tid] += t;
        __syncthreads();
    }
    if (tid < nBlocks) partial[tid] = buf[tid] - v;
    if (tid == 0) last_slot[0] = nE;
}

__global__ __launch_bounds__(256) void k_writeptr(const int* __restrict__ deg,
                                                  const int* __restrict__ partial,
                                                  int* __restrict__ outp, int n) {
    int tid = threadIdx.x;
    int base = blockIdx.x * 1024 + tid * 4;
    int d[4];
    int s = 0;
#pragma unroll
    for (int k = 0; k < 4; ++k) {
        int i = base + k;
        d[k] = (i < n) ? deg[i] : 0;
        s += d[k];
    }
    __shared__ int buf[256];
    buf[tid] = s;
    __syncthreads();
    for (int dd = 1; dd < 256; dd <<= 1) {
        int t = (tid >= dd) ? buf[tid - dd] : 0;
        __syncthreads();
        buf[tid] += t;
        __syncthreads();
    }
    int off = partial[blockIdx.x] + buf[tid] - s;
#pragma unroll
    for (int k = 0; k < 4; ++k) {
        int i = base + k;
        if (i < n) {
            outp[i] = off;
            off += d[k];
        }
    }
}

// ---------------- bucket partition (bucket = dst>>6) ----------------
__global__ __launch_bounds__(256) void k_bcount(const int* __restrict__ dst,
                                                int* __restrict__ cnt,
                                                int nE, int chunkSz, int nBuckets) {
    __shared__ int h[1024];
    int c = blockIdx.x, tid = threadIdx.x;
    for (int i = tid; i < nBuckets; i += 256) h[i] = 0;
    __syncthreads();
    int beg = c * chunkSz;
    int end = beg + chunkSz; if (end > nE) end = nE;
    int e = beg + tid;
    for (; e + 256 < end; e += 512) {
        int d0 = dst[e];
        int d1 = dst[e + 256];
        atomicAdd(&h[d0 >> 6], 1);
        atomicAdd(&h[d1 >> 6], 1);
    }
    if (e < end) atomicAdd(&h[dst[e] >> 6], 1);
    __syncthreads();
    for (int i = tid; i < nBuckets; i += 256) cnt[i * NCHUNK + c] = h[i];
}

__global__ __launch_bounds__(256) void k_bscatter(const int* __restrict__ src,
                                                  const int* __restrict__ dst,
                                                  const int* __restrict__ eoff,
                                                  unsigned* __restrict__ ebuf,
                                                  int nE, int chunkSz, int nBuckets) {
    __shared__ int cur[1024];
    int c = blockIdx.x, tid = threadIdx.x;
    for (int i = tid; i < nBuckets; i += 256) cur[i] = eoff[i * NCHUNK + c];
    __syncthreads();
    int beg = c * chunkSz;
    int end = beg + chunkSz; if (end > nE) end = nE;
    int e = beg + tid;
    for (; e + 256 < end; e += 512) {
        int d0 = dst[e];
        int d1 = dst[e + 256];
        int s0 = src[e];
        int s1 = src[e + 256];
        int p0 = atomicAdd(&cur[d0 >> 6], 1);
        int p1 = atomicAdd(&cur[d1 >> 6], 1);
        ebuf[p0] = ((unsigned)(d0 & 63) << 16) | (unsigned)s0;  // nNodes<=65536
        ebuf[p1] = ((unsigned)(d1 & 63) << 16) | (unsigned)s1;
    }
    if (e < end) {
        int d = dst[e];
        int pos = atomicAdd(&cur[d >> 6], 1);
        ebuf[pos] = ((unsigned)(d & 63) << 16) | (unsigned)src[e];
    }
}

__global__ __launch_bounds__(256) void k_bfill(const unsigned* __restrict__ ebuf,
                                               const int* __restrict__ eoff,
                                               int* __restrict__ rowptr,
                                               int* __restrict__ col,
                                               int nNodes, int nE, int nBuckets) {
    __shared__ int deg[64], cur[64];
    int b = blockIdx.x, tid = threadIdx.x;
    int lo = eoff[b * NCHUNK];
    int hi = (b + 1 < nBuckets) ? eoff[(b + 1) * NCHUNK] : nE;
    if (tid < 64) deg[tid] = 0;
    __syncthreads();
    for (int e = lo + tid; e < hi; e += 256) atomicAdd(&deg[ebuf[e] >> 16], 1);
    __syncthreads();
    if (tid < 64) {
        int d = deg[tid];
        int s = d;
        for (int o = 1; o < 64; o <<= 1) {
            int t = __shfl_up(s, o, 64);
            if (tid >= o) s += t;
        }
        int st = s - d;
        cur[tid] = lo + st;
        int node = b * 64 + tid;
        if (node < nNodes) rowptr[node] = lo + st;
    }
    __syncthreads();
    for (int e = lo + tid; e < hi; e += 256) {
        unsigned pk = ebuf[e];
        int pos = atomicAdd(&cur[pk >> 16], 1);
        col[pos] = (int)(pk & 0xFFFFu);
    }
}

// ---------------- weight prep: W[k][f] fp32 -> W^T hi/lo bf16 swizzled tiles ----------------
__global__ __launch_bounds__(256) void k_wprep(const float* __restrict__ W1,
                                               const float* __restrict__ W2,
                                               unsigned short* __restrict__ wt) {
    __shared__ unsigned short s[8192];
    int b = blockIdx.x;
    int layer = b >> 1;
    const float* src = ((b & 1) ? W2 : W1) + (size_t)layer * 4096;
    int tid = threadIdx.x;
    int k = tid >> 2;
    int f0 = (tid & 3) * 16;
    const float* srcp = src + k * 64 + f0;
#pragma unroll
    for (int j4 = 0; j4 < 4; ++j4) {
        float4 wv = *(const float4*)(srcp + j4 * 4);
        float c[4] = {wv.x, wv.y, wv.z, wv.w};
        int f = f0 + j4 * 4;
#pragma unroll
        for (int j = 0; j < 4; ++j) {
            unsigned short h = f2bf(c[j]);
            int ix = swz_idx(f + j, k);
            s[ix] = h;
            s[4096 + ix] = f2bf(c[j] - bf2f(h));
        }
    }
    __syncthreads();
    uint4* dst = (uint4*)(wt + (size_t)b * 8192);
    const uint4* sp = (const uint4*)s;
#pragma unroll
    for (int it = 0; it < 4; ++it) dst[it * 256 + tid] = sp[it * 256 + tid];
}

// ---------------- per-stat reduction of block partials ----------------
__global__ __launch_bounds__(256) void k_statred(const float* __restrict__ pstat,
                                                 float* __restrict__ stats, int nb) {
    int j = blockIdx.x;
    int tid = threadIdx.x;
    float s = 0.f;
    for (int b = tid; b < nb; b += 256) s += pstat[(size_t)b * 128 + j];
    __shared__ float red[256];
    red[tid] = s;
    __syncthreads();
    for (int d = 128; d > 0; d >>= 1) {
        if (tid < d) red[tid] += red[tid + d];
        __syncthreads();
    }
    if (tid == 0) stats[j] = red[0];
}

// ---------------- fused BN(prev) + gather (fp16, 8 groups x 8 lanes x 16B) ----------------
// one load instruction fetches 8 neighbor rows; main loop 16 edges/iter (2 indep loads)
template <bool DOBN>
__global__ __launch_bounds__(256) void k_aggbn(const unsigned short* __restrict__ x16,
                                               const int* __restrict__ rowptr,
                                               const int* __restrict__ col,
                                               const float* __restrict__ stats,
                                               const float* __restrict__ gamma,
                                               const float* __restrict__ beta,
                                               unsigned short* __restrict__ hout,
                                               int nNodes, float invN) {
    int wid = threadIdx.x >> 6;
    int lane = threadIdx.x & 63;
    int g8 = lane >> 3;        // edge group 0..7
    int l8 = lane & 7;         // feature chunk of 8
    int n = blockIdx.x * 4 + wid;
    if (n >= nNodes) return;

    float sc[8], sh[8];
    if (DOBN) {
#pragma unroll
        for (int j = 0; j < 8; ++j) {
            int f = l8 * 8 + j;
            float m = stats[f] * invN;
            float var = stats[64 + f] * invN - m * m;
            sc[j] = gamma[f] * rsqrtf(var + 1e-5f);
            sh[j] = beta[f] - m * sc[j];
        }
    }

#define LOADROW8(IDX, OP)                                                    \
    {                                                                        \
        u16x8 uv = *(const u16x8*)(x16 + (size_t)(IDX) * 64 + l8 * 8);       \
        _Pragma("unroll")                                                    \
        for (int j = 0; j < 8; ++j) {                                        \
            float v = h2f(uv[j]);                                            \
            if (DOBN) v = fmaxf(fmaf(v, sc[j], sh[j]), 0.f);                 \
            OP;                                                              \
        }                                                                    \
    }

    float acc[8] = {0.f, 0.f, 0.f, 0.f, 0.f, 0.f, 0.f, 0.f};
    if (g8 == 0) {
        LOADROW8(n, acc[j] = v)
    }

    int lo = rowptr[n], hi = rowptr[n + 1];
    int e = lo;
    for (; e + 16 <= hi; e += 16) {
        int i0 = col[e + g8];
        int i1 = col[e + 8 + g8];
        float t[8];
        LOADROW8(i0, t[j] = v)
        LOADROW8(i1, t[j] += v)
#pragma unroll
        for (int j = 0; j < 8; ++j) acc[j] += t[j];
    }
    for (; e + 8 <= hi; e += 8) {
        int i0 = col[e + g8];
        LOADROW8(i0, acc[j] += v)
    }
    if (e < hi) {
        int ee = e + g8;
        bool ok = ee < hi;
        int idx = col[ok ? ee : (hi - 1)];
        float t[8];
        LOADROW8(idx, t[j] = v)
        if (ok) {
#pragma unroll
            for (int j = 0; j < 8; ++j) acc[j] += t[j];
        }
    }
#undef LOADROW8

#pragma unroll
    for (int j = 0; j < 8; ++j) {
        acc[j] += __shfl_xor(acc[j], 8, 64);
        acc[j] += __shfl_xor(acc[j], 16, 64);
        acc[j] += __shfl_xor(acc[j], 32, 64);
    }

    if (lane < 8) {
        u16x8 o;
#pragma unroll
        for (int j = 0; j < 8; ++j) o[j] = f2h(acc[j]);
        *(u16x8*)(hout + (size_t)n * 64 + lane * 8) = o;
    }
}

// ---------------- MFMA 2-layer MLP: fp16 I/O, split bf16 hi/lo ----------------
__global__ __launch_bounds__(256, 5) void k_mlp(const unsigned short* __restrict__ h_in,
                                                unsigned short* __restrict__ h_out,
                                                const unsigned short* __restrict__ wt1,
                                                const float* __restrict__ b1,
                                                const unsigned short* __restrict__ wt2,
                                                const float* __restrict__ b2,
                                                float* __restrict__ pstat,
                                                int nNodes) {
    __shared__ __align__(16) unsigned short smem16[16384];   // 32KB
    unsigned short* sA_hi = smem16;
    unsigned short* sA_lo = smem16 + 4096;
    unsigned short* sW_hi = smem16 + 8192;
    unsigned short* sW_lo = smem16 + 12288;

    int tid = threadIdx.x;
    int n0 = blockIdx.x * 64;
    int lane = tid & 63;
    int w = tid >> 6;
    int lr = lane & 15;
    int q = lane >> 4;
    int r0 = w * 16;

    uint4 w2r[4];
#pragma unroll
    for (int it = 0; it < 4; ++it) w2r[it] = ((const uint4*)wt2)[it * 256 + tid];

#pragma unroll
    for (int it = 0; it < 2; ++it) {
        int idx = it * 256 + tid;
        int row = idx >> 3, ch = idx & 7;
        u16x8 iv = (u16x8)(0);
        if (n0 + row < nNodes)
            iv = *(const u16x8*)(h_in + (size_t)(n0 + row) * 64 + ch * 8);
        u16x8 hv, lv;
#pragma unroll
        for (int j = 0; j < 8; ++j) {
            float f = h2f(iv[j]);
            unsigned short h = f2bf(f);
            hv[j] = h;
            lv[j] = f2bf(f - bf2f(h));
        }
        int off = row * 64 + ((ch ^ (row & 7)) << 3);
        *(u16x8*)(sA_hi + off) = hv;
        *(u16x8*)(sA_lo + off) = lv;
    }
    {
        uint4* d = (uint4*)sW_hi;
        const uint4* s = (const uint4*)wt1;
#pragma unroll
        for (int it = 0; it < 4; ++it) d[it * 256 + tid] = s[it * 256 + tid];
    }
    __syncthreads();

    f32x4 acc[4];

#define GEMM_SPLIT(BIAS)                                                         \
    {                                                                            \
        int rowA = r0 + lr;                                                      \
        const unsigned short* pah = sA_hi + rowA * 64;                           \
        const unsigned short* pal = sA_lo + rowA * 64;                           \
        int sr = rowA & 7;                                                       \
        bf16x8 ah0 = *(const bf16x8*)(pah + ((q ^ sr) << 3));                    \
        bf16x8 ah1 = *(const bf16x8*)(pah + (((4 + q) ^ sr) << 3));              \
        bf16x8 al0 = *(const bf16x8*)(pal + ((q ^ sr) << 3));                    \
        bf16x8 al1 = *(const bf16x8*)(pal + (((4 + q) ^ sr) << 3));              \
        _Pragma("unroll")                                                        \
        for (int ct = 0; ct < 4; ++ct) {                                         \
            int f = ct * 16 + lr;                                                \
            const unsigned short* pbh = sW_hi + f * 64;                          \
            const unsigned short* pbl = sW_lo + f * 64;                          \
            int sf = f & 7;                                                      \
            bf16x8 bh0 = *(const bf16x8*)(pbh + ((q ^ sf) << 3));                \
            bf16x8 bh1 = *(const bf16x8*)(pbh + (((4 + q) ^ sf) << 3));          \
            bf16x8 bl0 = *(const bf16x8*)(pbl + ((q ^ sf) << 3));                \
            bf16x8 bl1 = *(const bf16x8*)(pbl + (((4 + q) ^ sf) << 3));          \
            float bias = BIAS[f];                                                \
            f32x4 c = {bias, bias, bias, bias};                                  \
            c = __builtin_amdgcn_mfma_f32_16x16x32_bf16(al0, bh0, c, 0, 0, 0);   \
            c = __builtin_amdgcn_mfma_f32_16x16x32_bf16(al1, bh1, c, 0, 0, 0);   \
            c = __builtin_amdgcn_mfma_f32_16x16x32_bf16(ah0, bl0, c, 0, 0, 0);   \
            c = __builtin_amdgcn_mfma_f32_16x16x32_bf16(ah1, bl1, c, 0, 0, 0);   \
            c = __builtin_amdgcn_mfma_f32_16x16x32_bf16(ah0, bh0, c, 0, 0, 0);   \
            c = __builtin_amdgcn_mfma_f32_16x16x32_bf16(ah1, bh1, c, 0, 0, 0);   \
            acc[ct] = c;                                                         \
        }                                                                        \
    }

    GEMM_SPLIT(b1)

    __syncthreads();

#pragma unroll
    for (int ct = 0; ct < 4; ++ct) {
        int f = ct * 16 + lr;
#pragma unroll
        for (int rg = 0; rg < 4; ++rg) {
            int row = r0 + q * 4 + rg;
            float v = fmaxf(acc[ct][rg], 0.f);
            unsigned short h = f2bf(v);
            int ix = swz_idx(row, f);
            sA_hi[ix] = h;
            sA_lo[ix] = f2bf(v - bf2f(h));
        }
    }
    {
        uint4* d = (uint4*)sW_hi;
#pragma unroll
        for (int it = 0; it < 4; ++it) d[it * 256 + tid] = w2r[it];
    }
    __syncthreads();

    GEMM_SPLIT(b2)

    __syncthreads();
#undef GEMM_SPLIT

    float* sS = (float*)sW_hi;
    float* sQ = sS + 256;

#pragma unroll
    for (int ct = 0; ct < 4; ++ct) {
        int f = ct * 16 + lr;
        float sp = 0.f, qp = 0.f;
#pragma unroll
        for (int rg = 0; rg < 4; ++rg) {
            int row = r0 + q * 4 + rg;
            float v = fmaxf(acc[ct][rg], 0.f);
            if (n0 + row < nNodes) {
                unsigned short hv = f2h(v);
                h_out[(size_t)(n0 + row) * 64 + f] = hv;
                float vq = h2f(hv);
                sp += vq;
                qp += vq * vq;
            }
        }
        sp += __shfl_xor(sp, 16, 64); qp += __shfl_xor(qp, 16, 64);
        sp += __shfl_xor(sp, 32, 64); qp += __shfl_xor(qp, 32, 64);
        if (q == 0) {
            sS[w * 64 + f] = sp;
            sQ[w * 64 + f] = qp;
        }
    }
    __syncthreads();
    if (tid < 128) {
        float v;
        if (tid < 64)
            v = sS[tid] + sS[64 + tid] + sS[128 + tid] + sS[192 + tid];
        else {
            int f = tid - 64;
            v = sQ[f] + sQ[64 + f] + sQ[128 + f] + sQ[192 + f];
        }
        pstat[(size_t)blockIdx.x * 128 + tid] = v;
    }
}

// ---------------- pooling (BN3 fused, fp16 in) + final GEMV ----------------
__device__ __forceinline__ int lower_bound_dev(const int* a, int n, int key) {
    int lo = 0, hi = n;
    while (lo < hi) {
        int mid = (lo + hi) >> 1;
        if (a[mid] < key) lo = mid + 1; else hi = mid;
    }
    return lo;
}

__global__ __launch_bounds__(256) void k_pool(const unsigned short* __restrict__ x16,
                                              const int* __restrict__ batch,
                                              const float* __restrict__ stats,
                                              const float* __restrict__ gamma,
                                              const float* __restrict__ beta,
                                              const float* __restrict__ Wf,
                                              const float* __restrict__ bf,
                                              float* __restrict__ out,
                                              int nNodes, float invN) {
    int wid = threadIdx.x >> 6;
    int lane = threadIdx.x & 63;
    int grp = lane >> 4;
    int l16 = lane & 15;
    int g = blockIdx.x * 4 + wid;

    float4 sc, sh;
    {
        float4 s  = ((const float4*)stats)[l16];
        float4 q  = ((const float4*)stats)[16 + l16];
        float4 ga = ((const float4*)gamma)[l16];
        float4 be = ((const float4*)beta)[l16];
        float m;
        m = s.x * invN; sc.x = ga.x * rsqrtf(q.x * invN - m * m + 1e-5f); sh.x = be.x - m * sc.x;
        m = s.y * invN; sc.y = ga.y * rsqrtf(q.y * invN - m * m + 1e-5f); sh.y = be.y - m * sc.y;
        m = s.z * invN; sc.z = ga.z * rsqrtf(q.z * invN - m * m + 1e-5f); sh.z = be.z - m * sc.z;
        m = s.w * invN; sc.w = ga.w * rsqrtf(q.w * invN - m * m + 1e-5f); sh.w = be.w - m * sc.w;
    }

    int lo = lower_bound_dev(batch, nNodes, g);
    int hi = lower_bound_dev(batch, nNodes, g + 1);

    float4 acc = f4zero();
    for (int r = lo + grp; r < hi; r += 4) {
        ushort4 uv = *(const ushort4*)(x16 + (size_t)r * 64 + l16 * 4);
        acc.x += fmaxf(fmaf(h2f(uv.x), sc.x, sh.x), 0.f);
        acc.y += fmaxf(fmaf(h2f(uv.y), sc.y, sh.y), 0.f);
        acc.z += fmaxf(fmaf(h2f(uv.z), sc.z, sh.z), 0.f);
        acc.w += fmaxf(fmaf(h2f(uv.w), sc.w, sh.w), 0.f);
    }
    acc.x += __shfl_xor(acc.x, 16, 64); acc.y += __shfl_xor(acc.y, 16, 64);
    acc.z += __shfl_xor(acc.z, 16, 64); acc.w += __shfl_xor(acc.w, 16, 64);
    acc.x += __shfl_xor(acc.x, 32, 64); acc.y += __shfl_xor(acc.y, 32, 64);
    acc.z += __shfl_xor(acc.z, 32, 64); acc.w += __shfl_xor(acc.w, 32, 64);

    float4 wf = ((const float4*)Wf)[l16];
    float p = acc.x * wf.x + acc.y * wf.y + acc.z * wf.z + acc.w * wf.w;
    p += __shfl_xor(p, 1, 64);
    p += __shfl_xor(p, 2, 64);
    p += __shfl_xor(p, 4, 64);
    p += __shfl_xor(p, 8, 64);
    if (lane == 0) out[g] = p + bf[0];
}

extern "C" void kernel_launch(void* const* d_in, const int* in_sizes, int n_in,
                              void* d_out, int out_size, void* d_ws, size_t ws_size,
                              hipStream_t stream) {
    const float* x_in  = (const float*)d_in[0];
    const int*   ei    = (const int*)d_in[1];
    const int*   batch = (const int*)d_in[2];
    const float* W1    = (const float*)d_in[3];
    const float* b1    = (const float*)d_in[4];
    const float* W2    = (const float*)d_in[5];
    const float* b2    = (const float*)d_in[6];
    const float* gamma = (const float*)d_in[7];
    const float* beta  = (const float*)d_in[8];
    const float* Wf    = (const float*)d_in[9];
    const float* bf    = (const float*)d_in[10];

    const int nNodes = in_sizes[0] / HIDDEN_C;   // 50000 (pack assumes <= 65536)
    const int nE = in_sizes[1] / 2;              // 800000
    const int* src = ei;
    const int* dst = ei + nE;

    const int nBuckets = (nNodes + 63) / 64;         // 782
    const int nTot = nBuckets * NCHUNK;              // 200192
    const int chunkSz = (nE + NCHUNK - 1) / NCHUNK;  // 3125
    const int scanBlocks = (nTot + 1023) / 1024;     // 196 (<=256)
    const float invN = 1.f / (float)nNodes;

    const size_t NH = ((size_t)nNodes * HIDDEN_C * sizeof(unsigned short) + 255) & ~(size_t)255;  // 6.4MB
    char* ws = (char*)d_ws;
    unsigned short* x16 = (unsigned short*)ws;
    unsigned short* hA  = (unsigned short*)(ws + NH);
    unsigned short* hB  = (unsigned short*)(ws + 2 * NH);
    float*    stats   = (float*)(ws + 3 * NH);
    unsigned short* wtbuf = (unsigned short*)(ws + 3 * NH + 4096);
    float*    pstat   = (float*)(ws + 3 * NH + 4096 + 98304);
    int*      rowptr  = (int*)((char*)pstat + 409600);
    int*      partial = rowptr + nNodes + 64;
    int*      col     = partial + 256;
    unsigned* ebuf    = (unsigned*)hB;
    int*      cnt     = (int*)((char*)hB + (size_t)nE * 4);
    int*      eoff    = cnt + nTot + 64;

    const int mlpGrid = nBuckets;
    const int aggGrid = (nNodes + 3) / 4;
    const int cvtGrid = (nNodes * 16 + 255) / 256;

    k_xcvt<<<cvtGrid, 256, 0, stream>>>((const float4*)x_in, (ushort4*)x16, nNodes * 16);
    k_wprep<<<6, 256, 0, stream>>>(W1, W2, wtbuf);
    k_bcount<<<NCHUNK, 256, 0, stream>>>(dst, cnt, nE, chunkSz, nBuckets);
    k_blocksum<<<scanBlocks, 256, 0, stream>>>(cnt, partial, nTot);
    k_scanpartial<<<1, 256, 0, stream>>>(partial, rowptr + nNodes, scanBlocks, nE);
    k_writeptr<<<scanBlocks, 256, 0, stream>>>(cnt, partial, eoff, nTot);
    k_bscatter<<<NCHUNK, 256, 0, stream>>>(src, dst, eoff, ebuf, nE, chunkSz, nBuckets);
    k_bfill<<<nBuckets, 256, 0, stream>>>(ebuf, eoff, rowptr, col, nNodes, nE, nBuckets);

    const unsigned short* prev_h = x16;
    unsigned short* cur = hA;
    for (int i = 0; i < 3; ++i) {
        if (i == 0) {
            k_aggbn<false><<<aggGrid, 256, 0, stream>>>(prev_h, rowptr, col,
                                                        nullptr, nullptr, nullptr,
                                                        cur, nNodes, invN);
        } else {
            k_aggbn<true><<<aggGrid, 256, 0, stream>>>(prev_h, rowptr, col,
                                                       stats + (size_t)(i - 1) * 128,
                                                       gamma + (size_t)(i - 1) * 64,
                                                       beta + (size_t)(i - 1) * 64,
                                                       cur, nNodes, invN);
        }
        k_mlp<<<mlpGrid, 256, 0, stream>>>(cur, cur,
                                           wtbuf + (size_t)(2 * i) * 8192, b1 + (size_t)i * 64,
                                           wtbuf + (size_t)(2 * i + 1) * 8192, b2 + (size_t)i * 64,
                                           pstat, nNodes);
        k_statred<<<128, 256, 0, stream>>>(pstat, stats + (size_t)i * 128, nBuckets);
        prev_h = cur;
        cur = (cur == hA) ? hB : hA;
    }

    k_pool<<<64, 256, 0, stream>>>(prev_h, batch, stats + 256, gamma + 128, beta + 128,
                                   Wf, bf, (float*)d_out, nNodes, invN);
}